// Round 11
// baseline (1136.971 us; speedup 1.0000x reference)
//
#include <hip/hip_runtime.h>

// ---------------------------------------------------------------------------
// ConditionedLatentSDETransition — MI355X (round 11: DAG restructure)
//
// Verified: inputs fp32 (runtime-detected), outputs fp32, ws >= 40MB (268MB),
// dict-order inputs. Round-10: 1111 us, absmax 0.0156.
//
// Round-11:
//  * x1t: X1 and T merged into one N=1536 GEMM (W1||Wd1 concat), 768 blocks.
//  * x2g: X2 (512 blocks) and G (512 blocks) packed in one 1024-block launch.
//  * fupd: F-GEMM with fused Euler update (z += h*F + sh*G*eps); final step
//    also emits out0 = z_new + Ub.
//  * final1 eliminated: Ub = dt*ut@Bsde^T precomputed once;
//    yt = z@C^T + dt*ut@Deff^T with Deff = C@Bsde + D (precomputed).
//  * bn_norm uses 16B loads. Launches 62 -> ~46.
// ---------------------------------------------------------------------------

typedef unsigned short ushort_t;
typedef __bf16 bf16x8 __attribute__((ext_vector_type(8)));
typedef float f32x4 __attribute__((ext_vector_type(4)));

__device__ __forceinline__ float bf2f(ushort_t s) {
  unsigned u = ((unsigned)s) << 16;
  return __uint_as_float(u);
}
__device__ __forceinline__ ushort_t f2bf(float f) {
  unsigned u = __float_as_uint(f);
  unsigned lsb = (u >> 16) & 1u;
  u += 0x7fffu + lsb;
  return (ushort_t)(u >> 16);
}
__device__ __forceinline__ float ldin(const void* p, size_t i, int f32) {
  return f32 ? ((const float*)p)[i] : bf2f(((const ushort_t*)p)[i]);
}
__device__ __forceinline__ void async16(const void* g, void* l) {
  __builtin_amdgcn_global_load_lds(
      (const __attribute__((address_space(1))) void*)g,
      (__attribute__((address_space(3))) void*)l, 16, 0, 0);
}

// consts: [0]=h, [1]=sqrt_h, [2]=dt, [3]=f32flag
__global__ void k_detect(const void* __restrict__ eps, const void* __restrict__ dtraw,
                         float* __restrict__ consts) {
  __shared__ float mx[256];
  const int t = threadIdx.x;
  const ushort_t* e = (const ushort_t*)eps;
  float m = 0.f;
#pragma unroll
  for (int k = 0; k < 4; ++k) {
    float v = fabsf(bf2f(e[t * 4 + k]));
    if (!(v < 1e30f)) v = 1e30f;
    m = fmaxf(m, v);
  }
  mx[t] = m;
  __syncthreads();
  if (t == 0) {
    float M = 0.f;
    for (int k = 0; k < 256; ++k) M = fmaxf(M, mx[k]);
    const int f32 = (M > 1e3f) ? 1 : 0;
    float dt;
    if (f32) {
      dt = *(const float*)dtraw;
    } else {
      float db = bf2f(*(const ushort_t*)dtraw);
      float df = *(const float*)dtraw;
      dt = (db > 1e-6f && db < 1e3f) ? db : df;
    }
    const float h = dt * 0.125f;
    consts[0] = h;
    consts[1] = sqrtf(fabsf(h) + 1e-8f);
    consts[2] = dt;
    consts[3] = (float)f32;
  }
}

// one-time: convert weights to bf16 canon: [W1 | Wd1 | W2 | W3 | Wd2]
struct ConvArgs { const void* src[5]; };
#define CONV_TOT 2621440

__global__ void k_conv(ConvArgs a, const float* __restrict__ consts,
                       ushort_t* __restrict__ base) {
  constexpr int CUM[6] = {0, 524288, 786432, 1835008, 2359296, 2621440};
  const int f32 = consts[3] != 0.f;
  const int i = (blockIdx.x * 256 + threadIdx.x) * 4;
  if (i >= CONV_TOT) return;
  int j = 0;
#pragma unroll
  for (int k = 1; k < 5; ++k)
    if (i >= CUM[k]) j = k;
  const int local = i - CUM[j];
  const void* s = a.src[j];
  ushort4 o;
  if (f32) {
    float4 v = ((const float4*)s)[local >> 2];
    o = make_ushort4(f2bf(v.x), f2bf(v.y), f2bf(v.z), f2bf(v.w));
  } else {
    o = ((const ushort4*)s)[local >> 2];
  }
  *(ushort4*)(base + i) = o;
}

// ---------------------------------------------------------------------------
// Generic MFMA GEMM body. BM = MT*64, BN=64, BK=64, 256 threads.
// MODE 0 plain, 1 tanh, 2 softplus+1e-5. BIAS: add bias[gn+ncol0].
// STATS: per-col sum/sumsq -> s1/s2 atomics. FUSE: Euler update epilogue.
// FINAL: (with FUSE) also out0 = z_new + Ub.
// Store column = gn + ncol0, row stride Nout.
// ---------------------------------------------------------------------------
template <int MT, int MODE, int STATS, int FUSE, int BIAS, int FINAL>
__device__ __forceinline__ void gemm_body(
    const ushort_t* __restrict__ A, const ushort_t* __restrict__ W,
    const void* __restrict__ bias, int ncol0, ushort_t* __restrict__ Cout,
    int Nout, int K, int m0, int n0, __bf16* As, __bf16* Bs,
    float* __restrict__ s1, float* __restrict__ s2,
    const ushort_t* __restrict__ Gb, float* __restrict__ zf,
    ushort_t* __restrict__ zb, const void* __restrict__ eps,
    unsigned long long eoff, const float* __restrict__ consts,
    const float* __restrict__ Ub, float* __restrict__ out0) {
  constexpr int BM = MT * 64;
  const int f32 = consts[3] != 0.f;
  const int tid = threadIdx.x;
  const int lane = tid & 63;
  const int wave = tid >> 6;
  const int col = lane & 15;
  const int quad = lane >> 4;
  const int rowBase = wave * (BM / 4);

  f32x4 acc[MT][4] = {};

  for (int k0 = 0; k0 < K; k0 += 64) {
#pragma unroll
    for (int j = 0; j < BM / 32; ++j) {
      int chunk = j * 256 + tid;
      int row = chunk >> 3;
      int kc = chunk & 7;
      async16(A + (size_t)(m0 + row) * K + k0 + kc * 8, (char*)As + chunk * 16);
    }
#pragma unroll
    for (int j = 0; j < 2; ++j) {
      int chunk = j * 256 + tid;
      int row = chunk >> 3;
      int kc = chunk & 7;
      async16(W + (size_t)(n0 + row) * K + k0 + kc * 8, (char*)Bs + chunk * 16);
    }
    __syncthreads();

#pragma unroll
    for (int kk = 0; kk < 2; ++kk) {
      const int kb = kk * 32 + quad * 8;
      bf16x8 af[MT], bfr[4];
#pragma unroll
      for (int mt = 0; mt < MT; ++mt)
        af[mt] = *(const bf16x8*)&As[(rowBase + mt * 16 + col) * 64 + kb];
#pragma unroll
      for (int nt = 0; nt < 4; ++nt)
        bfr[nt] = *(const bf16x8*)&Bs[(nt * 16 + col) * 64 + kb];
#pragma unroll
      for (int mt = 0; mt < MT; ++mt)
#pragma unroll
        for (int nt = 0; nt < 4; ++nt)
          acc[mt][nt] = __builtin_amdgcn_mfma_f32_16x16x32_bf16(
              af[mt], bfr[nt], acc[mt][nt], 0, 0, 0);
    }
    __syncthreads();
  }

  float* sS = (float*)As;       // [64] stats scratch (reuses As)
  float* sQ = (float*)As + 64;
  if (STATS) {
    if (tid < 128) ((float*)As)[tid] = 0.f;
    __syncthreads();
  }

  const float h = consts[0], sh = consts[1];

#pragma unroll
  for (int nt = 0; nt < 4; ++nt) {
    const int gn = n0 + nt * 16 + col;
    const float bv = BIAS ? ldin(bias, gn + ncol0, f32) : 0.f;
    float ls = 0.f, lq = 0.f;
#pragma unroll
    for (int mt = 0; mt < MT; ++mt) {
#pragma unroll
      for (int r = 0; r < 4; ++r) {
        const int gm = m0 + rowBase + mt * 16 + quad * 4 + r;
        float v = acc[mt][nt][r] + bv;
        if (STATS) {
          ls += v;
          lq += v * v;
        }
        if (MODE == 1) {
          v = tanhf(v);
        } else if (MODE == 2) {
          v = fmaxf(v, 0.f) + log1pf(expf(-fabsf(v))) + 1e-5f;
        }
        const size_t o = (size_t)gm * Nout + gn + ncol0;
        if (FUSE) {
          const float e = ldin(eps, eoff + o, f32);
          const float g = bf2f(Gb[o]);
          const float z = zf[o] + h * v + sh * g * e;
          zf[o] = z;
          zb[o] = f2bf(z);
          if (FINAL) out0[o] = z + Ub[o];
        } else {
          Cout[o] = f2bf(v);
        }
      }
    }
    if (STATS) {
      atomicAdd(&sS[nt * 16 + col], ls);
      atomicAdd(&sQ[nt * 16 + col], lq);
    }
  }

  if (STATS) {
    __syncthreads();
    if (tid < 64) {
      atomicAdd(&s1[n0 + tid], sS[tid]);
      atomicAdd(&s2[n0 + tid], sQ[tid]);
    }
  }
}

// X1 (cols 0..1023, stats) merged with T=tanh (cols 1024..1535). W = W1||Wd1.
__global__ __launch_bounds__(256, 3) void k_x1t(
    const ushort_t* __restrict__ zb, const ushort_t* __restrict__ Wcat,
    const void* __restrict__ bd1, ushort_t* __restrict__ Xb,
    ushort_t* __restrict__ Tb, float* __restrict__ s1, float* __restrict__ s2,
    const float* __restrict__ consts) {
  __shared__ __bf16 As[128 * 64] __attribute__((aligned(16)));
  __shared__ __bf16 Bs[64 * 64] __attribute__((aligned(16)));
  const int nb = blockIdx.x;  // 0..23
  const int m0 = blockIdx.y * 128, n0 = nb * 64;
  if (nb < 16) {
    gemm_body<2, 0, 1, 0, 0, 0>(zb, Wcat, nullptr, 0, Xb, 1024, 512, m0, n0,
                                As, Bs, s1, s2, nullptr, nullptr, nullptr,
                                nullptr, 0, consts, nullptr, nullptr);
  } else {
    gemm_body<2, 1, 0, 0, 1, 0>(zb, Wcat, bd1, -1024, Tb, 512, 512, m0, n0,
                                As, Bs, nullptr, nullptr, nullptr, nullptr,
                                nullptr, nullptr, 0, consts, nullptr, nullptr);
  }
}

// X2 (ids 0..511, stats) packed with G=softplus (ids 512..1023).
__global__ __launch_bounds__(256, 3) void k_x2g(
    const ushort_t* __restrict__ A1, const ushort_t* __restrict__ W2c,
    const ushort_t* __restrict__ Tb, const ushort_t* __restrict__ Wd2c,
    const void* __restrict__ bd2, ushort_t* __restrict__ Ab,
    ushort_t* __restrict__ Gb, float* __restrict__ s1, float* __restrict__ s2,
    const float* __restrict__ consts) {
  __shared__ __bf16 As[128 * 64] __attribute__((aligned(16)));
  __shared__ __bf16 Bs[64 * 64] __attribute__((aligned(16)));
  const int id = blockIdx.x;
  if (id < 512) {
    const int m0 = (id >> 4) * 128, n0 = (id & 15) * 64;
    gemm_body<2, 0, 1, 0, 0, 0>(A1, W2c, nullptr, 0, Ab, 1024, 1024, m0, n0,
                                As, Bs, s1, s2, nullptr, nullptr, nullptr,
                                nullptr, 0, consts, nullptr, nullptr);
  } else {
    const int gb = id - 512;
    const int m0 = (gb >> 3) * 64, n0 = (gb & 7) * 64;
    gemm_body<1, 2, 0, 0, 1, 0>(Tb, Wd2c, bd2, 0, Gb, 512, 512, m0, n0,
                                As, Bs, nullptr, nullptr, nullptr, nullptr,
                                nullptr, nullptr, 0, consts, nullptr, nullptr);
  }
}

// F = A2@W3^T + b3 with fused Euler update; FINAL also writes out0 = z + Ub.
template <int FINAL>
__global__ __launch_bounds__(256, 4) void k_fupd(
    const ushort_t* __restrict__ A2, const ushort_t* __restrict__ W3c,
    const void* __restrict__ b3, const ushort_t* __restrict__ Gb,
    float* __restrict__ zf, ushort_t* __restrict__ zb,
    const void* __restrict__ eps, unsigned long long eoff,
    const float* __restrict__ consts, const float* __restrict__ Ub,
    float* __restrict__ out0) {
  __shared__ __bf16 As[64 * 64] __attribute__((aligned(16)));
  __shared__ __bf16 Bs[64 * 64] __attribute__((aligned(16)));
  const int m0 = blockIdx.y * 64, n0 = blockIdx.x * 64;
  gemm_body<1, 0, 0, 1, 1, FINAL>(A2, W3c, b3, 0, nullptr, 512, 1024, m0, n0,
                                  As, Bs, nullptr, nullptr, Gb, zf, zb, eps,
                                  eoff, consts, Ub, out0);
}

// BN normalize + relu, in-place on bf16 X (8 elems/thread)
__global__ void bn_norm(ushort_t* __restrict__ X, const float* __restrict__ s1,
                        const float* __restrict__ s2, const void* __restrict__ g,
                        const void* __restrict__ be, const float* __restrict__ consts,
                        int N) {
  const int f32 = consts[3] != 0.f;
  const int i = blockIdx.x * 256 + threadIdx.x;
  const int c = (i * 8) % N;
  const float inv = 1.0f / 4096.0f;
  ushort4 x0 = ((const ushort4*)X)[i * 2];
  ushort4 x1 = ((const ushort4*)X)[i * 2 + 1];
  float xv[8] = {bf2f(x0.x), bf2f(x0.y), bf2f(x0.z), bf2f(x0.w),
                 bf2f(x1.x), bf2f(x1.y), bf2f(x1.z), bf2f(x1.w)};
  ushort_t o[8];
#pragma unroll
  for (int j = 0; j < 8; ++j) {
    float mu = s1[c + j] * inv;
    float var = fmaxf(s2[c + j] * inv - mu * mu, 0.f);
    float sc = ldin(g, c + j, f32) * rsqrtf(var + 1e-5f);
    float v = (xv[j] - mu) * sc + ldin(be, c + j, f32);
    o[j] = f2bf(fmaxf(v, 0.f));
  }
  ((ushort4*)X)[i * 2] = make_ushort4(o[0], o[1], o[2], o[3]);
  ((ushort4*)X)[i * 2 + 1] = make_ushort4(o[4], o[5], o[6], o[7]);
}

// zf (fp32 master) + zb (bf16 shadow) <- z_dyn
__global__ void k_init(const void* __restrict__ z, float* __restrict__ zf,
                       ushort_t* __restrict__ zb, const float* __restrict__ consts) {
  const int f32 = consts[3] != 0.f;
  const int i = blockIdx.x * 256 + threadIdx.x;
  float4 v;
  if (f32) {
    v = ((const float4*)z)[i];
  } else {
    ushort4 u = ((const ushort4*)z)[i];
    v = make_float4(bf2f(u.x), bf2f(u.y), bf2f(u.z), bf2f(u.w));
  }
  ((float4*)zf)[i] = v;
  ((ushort4*)zb)[i] = make_ushort4(f2bf(v.x), f2bf(v.y), f2bf(v.z), f2bf(v.w));
}

// Ub = dt*(ut@Bsde^T), fp32 (4096x512), LDS-tiled 64x64 K=64
__global__ __launch_bounds__(256) void k_ub(
    const void* __restrict__ ut, const void* __restrict__ Bsde,
    const float* __restrict__ consts, float* __restrict__ Ub) {
  __shared__ float As[64][68];
  __shared__ float Bs[64][68];
  const float dt = consts[2];
  const int f32 = consts[3] != 0.f;
  const int t = threadIdx.x;
  const int tx = t & 15, ty = t >> 4;
  const int n0 = blockIdx.x * 64, m0 = blockIdx.y * 64;
  const int r = t >> 2;
  const int c0 = (t & 3) * 16;

#pragma unroll
  for (int j = 0; j < 16; ++j) {
    As[c0 + j][r] = ldin(ut, (size_t)(m0 + r) * 64 + c0 + j, f32);
    Bs[c0 + j][r] = ldin(Bsde, (size_t)(n0 + r) * 64 + c0 + j, f32);
  }
  __syncthreads();

  float acc[4][4] = {};
#pragma unroll 8
  for (int kk = 0; kk < 64; ++kk) {
    float a[4], b[4];
    *(float4*)a = *(const float4*)&As[kk][ty * 4];
    *(float4*)b = *(const float4*)&Bs[kk][tx * 4];
#pragma unroll
    for (int i = 0; i < 4; ++i)
#pragma unroll
      for (int j = 0; j < 4; ++j) acc[i][j] += a[i] * b[j];
  }

#pragma unroll
  for (int i = 0; i < 4; ++i) {
    const size_t o = (size_t)(m0 + ty * 4 + i) * 512 + n0 + tx * 4;
    *(float4*)&Ub[o] = make_float4(dt * acc[i][0], dt * acc[i][1],
                                   dt * acc[i][2], dt * acc[i][3]);
  }
}

// Deff[j][k] = D[j][k] + sum_l C[j][l]*Bsde[l][k]   (25x64)
__global__ void k_deff(const void* __restrict__ Cm, const void* __restrict__ Bsde,
                       const void* __restrict__ Dm, const float* __restrict__ consts,
                       float* __restrict__ Deff) {
  const int f32 = consts[3] != 0.f;
  const int j = blockIdx.x;   // 0..24
  const int k = threadIdx.x;  // 0..63
  float acc = ldin(Dm, (size_t)j * 64 + k, f32);
  for (int l = 0; l < 512; ++l)
    acc += ldin(Cm, (size_t)j * 512 + l, f32) * ldin(Bsde, (size_t)l * 64 + k, f32);
  Deff[j * 64 + k] = acc;
}

// yt = zf@C^T + dt*(ut@Deff^T): wave-per-row
__global__ __launch_bounds__(256) void k_final2(
    const float* __restrict__ zf, const void* __restrict__ ut,
    const float* __restrict__ consts, const void* __restrict__ Cm,
    const float* __restrict__ Deff, float* __restrict__ out1) {
  const float dt = consts[2];
  const int f32 = consts[3] != 0.f;
  const int t = threadIdx.x;
  const int lane = t & 63;
  const int m = blockIdx.x * 4 + (t >> 6);
  float z8[8];
#pragma unroll
  for (int i = 0; i < 8; ++i) z8[i] = zf[(size_t)m * 512 + i * 64 + lane];
  const float u = ldin(ut, (size_t)m * 64 + lane, f32);

  for (int j = 0; j < 25; ++j) {
    float p = dt * u * Deff[j * 64 + lane];
#pragma unroll
    for (int i = 0; i < 8; ++i)
      p += z8[i] * ldin(Cm, (size_t)j * 512 + i * 64 + lane, f32);
#pragma unroll
    for (int off = 32; off > 0; off >>= 1) p += __shfl_down(p, off, 64);
    if (lane == 0) out1[m * 25 + j] = p;
  }
}

// ---------------------------------------------------------------------------
extern "C" void kernel_launch(void* const* d_in, const int* in_sizes, int n_in,
                              void* d_out, int out_size, void* d_ws, size_t ws_size,
                              hipStream_t stream) {
  static const int expA[22] = {
      2097152, 524288, 1,      262144, 16777216, 524288, 1024, 1024,
      1024,    1048576, 1024,  1024,   1024,     524288, 512,  262144,
      512,     262144, 512,    32768,  12800,    1600};

  int map[21];
  bool okA = (n_in == 22), okB = (n_in == 21);
  if (okA)
    for (int i = 0; i < 22; ++i)
      if (in_sizes[i] != expA[i]) { okA = false; break; }
  if (okB) {
    int j = 0;
    for (int i = 0; i < 22; ++i) {
      if (i == 1) continue;
      if (in_sizes[j] != expA[i]) { okB = false; break; }
      ++j;
    }
  }
  if (okA) {
    map[0] = 0;
    for (int i = 1; i < 21; ++i) map[i] = i + 1;
  } else if (okB) {
    for (int i = 0; i < 21; ++i) map[i] = i;
  } else {
    map[0] = 0;
    for (int i = 1; i < 21; ++i) map[i] = (i + 1 < n_in) ? i + 1 : n_in - 1;
  }

  const void* z_dyn = d_in[map[0]];
  const void* dtp = d_in[map[1]];
  const void* ut = d_in[map[2]];
  const void* eps = d_in[map[3]];
  const void* W1 = d_in[map[4]];
  const void* g1 = d_in[map[6]];
  const void* be1 = d_in[map[7]];
  const void* W2 = d_in[map[8]];
  const void* g2 = d_in[map[10]];
  const void* be2 = d_in[map[11]];
  const void* W3 = d_in[map[12]];
  const void* b3 = d_in[map[13]];
  const void* Wd1 = d_in[map[14]];
  const void* bd1 = d_in[map[15]];
  const void* Wd2 = d_in[map[16]];
  const void* bd2 = d_in[map[17]];
  const void* Bsde = d_in[map[18]];
  const void* Cm = d_in[map[19]];
  const void* Dm = d_in[map[20]];

  // ws layout (~50 MB of 268 MB):
  //  [0,8M) zf fp32; [8,12M) zb bf16
  //  [12,20M) Xb bf16 (X1/A1)
  //  [20,28M) Ab bf16 (X2/A2)
  //  [28,32M) Tb bf16; [32,36M) Gb bf16
  //  [36,44M) Ub fp32
  //  [44,49.25M) canon bf16 weights [W1|Wd1|W2|W3|Wd2]
  //  [49.5M) stats 16x2048 f32, consts, Deff
  char* ws = (char*)d_ws;
  const size_t MB = 1024 * 1024;
  float* zf = (float*)(ws + 0);
  ushort_t* zb = (ushort_t*)(ws + 8 * MB);
  ushort_t* Xb = (ushort_t*)(ws + 12 * MB);
  ushort_t* Ab = (ushort_t*)(ws + 20 * MB);
  ushort_t* Tb = (ushort_t*)(ws + 28 * MB);
  ushort_t* Gb = (ushort_t*)(ws + 32 * MB);
  float* Ub = (float*)(ws + 36 * MB);
  ushort_t* canon = (ushort_t*)(ws + 44 * MB);
  float* stats = (float*)(ws + 49 * MB + 512 * 1024);
  float* consts = stats + 16 * 2048;
  float* Deff = consts + 16;

  const ushort_t* Wcat = canon + 0;        // W1(1024)||Wd1(512) rows, K=512
  const ushort_t* W2c = canon + 786432;    // 1024 rows, K=1024
  const ushort_t* W3c = canon + 1835008;   // 512 rows, K=1024
  const ushort_t* Wd2c = canon + 2359296;  // 512 rows, K=512

  float* out_z = (float*)d_out;
  float* out_y = out_z + 4096 * 512;

  const dim3 blk(256);

  k_detect<<<1, blk, 0, stream>>>(eps, dtp, consts);

  ConvArgs ca;
  ca.src[0] = W1;
  ca.src[1] = Wd1;
  ca.src[2] = W2;
  ca.src[3] = W3;
  ca.src[4] = Wd2;
  k_conv<<<(CONV_TOT / 4 + 255) / 256, blk, 0, stream>>>(ca, consts, canon);

  hipMemsetAsync(stats, 0, 16 * 2048 * sizeof(float), stream);
  k_init<<<2048, blk, 0, stream>>>(z_dyn, zf, zb, consts);
  k_ub<<<dim3(8, 64), blk, 0, stream>>>(ut, Bsde, consts, Ub);
  k_deff<<<25, 64, 0, stream>>>(Cm, Bsde, Dm, consts, Deff);

  for (int s = 0; s < 8; ++s) {
    float* sA1 = stats + (s * 2 + 0) * 2048;
    float* sA2 = stats + (s * 2 + 1) * 2048;
    const unsigned long long eoff = (unsigned long long)s * 4096 * 512;

    // X1 (stats, no bias) || T = tanh(z@Wd1^T+bd1)
    k_x1t<<<dim3(24, 32), blk, 0, stream>>>(zb, Wcat, bd1, Xb, Tb,
                                            sA1, sA1 + 1024, consts);
    bn_norm<<<2048, blk, 0, stream>>>(Xb, sA1, sA1 + 1024, g1, be1, consts, 1024);

    // X2 (stats, no bias) packed with G = softplus(T@Wd2^T+bd2)+1e-5
    k_x2g<<<1024, blk, 0, stream>>>(Xb, W2c, Tb, Wd2c, bd2, Ab, Gb,
                                    sA2, sA2 + 1024, consts);
    bn_norm<<<2048, blk, 0, stream>>>(Ab, sA2, sA2 + 1024, g2, be2, consts, 1024);

    // F = A2@W3^T + b3, fused z += h*F + sh*G*eps; final step emits out0
    if (s < 7) {
      k_fupd<0><<<dim3(8, 64), blk, 0, stream>>>(Ab, W3c, b3, Gb, zf, zb, eps,
                                                 eoff, consts, Ub, out_z);
    } else {
      k_fupd<1><<<dim3(8, 64), blk, 0, stream>>>(Ab, W3c, b3, Gb, zf, zb, eps,
                                                 eoff, consts, Ub, out_z);
    }
  }

  k_final2<<<1024, blk, 0, stream>>>(zf, ut, consts, Cm, Deff, out_y);
}

// Round 12
// 1088.322 us; speedup vs baseline: 1.0447x; 1.0447x over previous
//
#include <hip/hip_runtime.h>

// ---------------------------------------------------------------------------
// ConditionedLatentSDETransition — MI355X (round 12: fix k_deff occupancy)
//
// Verified: inputs fp32 (runtime-detected), outputs fp32, ws ~268MB,
// dict-order inputs. Round-11: 1137 us, absmax 0.031 (k_deff was 65 us
// at 0.26% occupancy — 25 waves total, serial 512-iter dot products).
//
// Round-12:
//  * k_deff: 25 blocks x 256 threads, 4-way l-split + LDS reduce.
//  * k_x2g: __launch_bounds__(256,4) — 4 blocks/CU for the 1024-block grid.
//  * Rest identical to round 11.
// ---------------------------------------------------------------------------

typedef unsigned short ushort_t;
typedef __bf16 bf16x8 __attribute__((ext_vector_type(8)));
typedef float f32x4 __attribute__((ext_vector_type(4)));

__device__ __forceinline__ float bf2f(ushort_t s) {
  unsigned u = ((unsigned)s) << 16;
  return __uint_as_float(u);
}
__device__ __forceinline__ ushort_t f2bf(float f) {
  unsigned u = __float_as_uint(f);
  unsigned lsb = (u >> 16) & 1u;
  u += 0x7fffu + lsb;
  return (ushort_t)(u >> 16);
}
__device__ __forceinline__ float ldin(const void* p, size_t i, int f32) {
  return f32 ? ((const float*)p)[i] : bf2f(((const ushort_t*)p)[i]);
}
__device__ __forceinline__ void async16(const void* g, void* l) {
  __builtin_amdgcn_global_load_lds(
      (const __attribute__((address_space(1))) void*)g,
      (__attribute__((address_space(3))) void*)l, 16, 0, 0);
}

// consts: [0]=h, [1]=sqrt_h, [2]=dt, [3]=f32flag
__global__ void k_detect(const void* __restrict__ eps, const void* __restrict__ dtraw,
                         float* __restrict__ consts) {
  __shared__ float mx[256];
  const int t = threadIdx.x;
  const ushort_t* e = (const ushort_t*)eps;
  float m = 0.f;
#pragma unroll
  for (int k = 0; k < 4; ++k) {
    float v = fabsf(bf2f(e[t * 4 + k]));
    if (!(v < 1e30f)) v = 1e30f;
    m = fmaxf(m, v);
  }
  mx[t] = m;
  __syncthreads();
  if (t == 0) {
    float M = 0.f;
    for (int k = 0; k < 256; ++k) M = fmaxf(M, mx[k]);
    const int f32 = (M > 1e3f) ? 1 : 0;
    float dt;
    if (f32) {
      dt = *(const float*)dtraw;
    } else {
      float db = bf2f(*(const ushort_t*)dtraw);
      float df = *(const float*)dtraw;
      dt = (db > 1e-6f && db < 1e3f) ? db : df;
    }
    const float h = dt * 0.125f;
    consts[0] = h;
    consts[1] = sqrtf(fabsf(h) + 1e-8f);
    consts[2] = dt;
    consts[3] = (float)f32;
  }
}

// one-time: convert weights to bf16 canon: [W1 | Wd1 | W2 | W3 | Wd2]
struct ConvArgs { const void* src[5]; };
#define CONV_TOT 2621440

__global__ void k_conv(ConvArgs a, const float* __restrict__ consts,
                       ushort_t* __restrict__ base) {
  constexpr int CUM[6] = {0, 524288, 786432, 1835008, 2359296, 2621440};
  const int f32 = consts[3] != 0.f;
  const int i = (blockIdx.x * 256 + threadIdx.x) * 4;
  if (i >= CONV_TOT) return;
  int j = 0;
#pragma unroll
  for (int k = 1; k < 5; ++k)
    if (i >= CUM[k]) j = k;
  const int local = i - CUM[j];
  const void* s = a.src[j];
  ushort4 o;
  if (f32) {
    float4 v = ((const float4*)s)[local >> 2];
    o = make_ushort4(f2bf(v.x), f2bf(v.y), f2bf(v.z), f2bf(v.w));
  } else {
    o = ((const ushort4*)s)[local >> 2];
  }
  *(ushort4*)(base + i) = o;
}

// ---------------------------------------------------------------------------
// Generic MFMA GEMM body. BM = MT*64, BN=64, BK=64, 256 threads.
// MODE 0 plain, 1 tanh, 2 softplus+1e-5. BIAS: add bias[gn+ncol0].
// STATS: per-col sum/sumsq -> s1/s2 atomics. FUSE: Euler update epilogue.
// FINAL: (with FUSE) also out0 = z_new + Ub.
// ---------------------------------------------------------------------------
template <int MT, int MODE, int STATS, int FUSE, int BIAS, int FINAL>
__device__ __forceinline__ void gemm_body(
    const ushort_t* __restrict__ A, const ushort_t* __restrict__ W,
    const void* __restrict__ bias, int ncol0, ushort_t* __restrict__ Cout,
    int Nout, int K, int m0, int n0, __bf16* As, __bf16* Bs,
    float* __restrict__ s1, float* __restrict__ s2,
    const ushort_t* __restrict__ Gb, float* __restrict__ zf,
    ushort_t* __restrict__ zb, const void* __restrict__ eps,
    unsigned long long eoff, const float* __restrict__ consts,
    const float* __restrict__ Ub, float* __restrict__ out0) {
  constexpr int BM = MT * 64;
  const int f32 = consts[3] != 0.f;
  const int tid = threadIdx.x;
  const int lane = tid & 63;
  const int wave = tid >> 6;
  const int col = lane & 15;
  const int quad = lane >> 4;
  const int rowBase = wave * (BM / 4);

  f32x4 acc[MT][4] = {};

  for (int k0 = 0; k0 < K; k0 += 64) {
#pragma unroll
    for (int j = 0; j < BM / 32; ++j) {
      int chunk = j * 256 + tid;
      int row = chunk >> 3;
      int kc = chunk & 7;
      async16(A + (size_t)(m0 + row) * K + k0 + kc * 8, (char*)As + chunk * 16);
    }
#pragma unroll
    for (int j = 0; j < 2; ++j) {
      int chunk = j * 256 + tid;
      int row = chunk >> 3;
      int kc = chunk & 7;
      async16(W + (size_t)(n0 + row) * K + k0 + kc * 8, (char*)Bs + chunk * 16);
    }
    __syncthreads();

#pragma unroll
    for (int kk = 0; kk < 2; ++kk) {
      const int kb = kk * 32 + quad * 8;
      bf16x8 af[MT], bfr[4];
#pragma unroll
      for (int mt = 0; mt < MT; ++mt)
        af[mt] = *(const bf16x8*)&As[(rowBase + mt * 16 + col) * 64 + kb];
#pragma unroll
      for (int nt = 0; nt < 4; ++nt)
        bfr[nt] = *(const bf16x8*)&Bs[(nt * 16 + col) * 64 + kb];
#pragma unroll
      for (int mt = 0; mt < MT; ++mt)
#pragma unroll
        for (int nt = 0; nt < 4; ++nt)
          acc[mt][nt] = __builtin_amdgcn_mfma_f32_16x16x32_bf16(
              af[mt], bfr[nt], acc[mt][nt], 0, 0, 0);
    }
    __syncthreads();
  }

  float* sS = (float*)As;       // [64] stats scratch (reuses As)
  float* sQ = (float*)As + 64;
  if (STATS) {
    if (tid < 128) ((float*)As)[tid] = 0.f;
    __syncthreads();
  }

  const float h = consts[0], sh = consts[1];

#pragma unroll
  for (int nt = 0; nt < 4; ++nt) {
    const int gn = n0 + nt * 16 + col;
    const float bv = BIAS ? ldin(bias, gn + ncol0, f32) : 0.f;
    float ls = 0.f, lq = 0.f;
#pragma unroll
    for (int mt = 0; mt < MT; ++mt) {
#pragma unroll
      for (int r = 0; r < 4; ++r) {
        const int gm = m0 + rowBase + mt * 16 + quad * 4 + r;
        float v = acc[mt][nt][r] + bv;
        if (STATS) {
          ls += v;
          lq += v * v;
        }
        if (MODE == 1) {
          v = tanhf(v);
        } else if (MODE == 2) {
          v = fmaxf(v, 0.f) + log1pf(expf(-fabsf(v))) + 1e-5f;
        }
        const size_t o = (size_t)gm * Nout + gn + ncol0;
        if (FUSE) {
          const float e = ldin(eps, eoff + o, f32);
          const float g = bf2f(Gb[o]);
          const float z = zf[o] + h * v + sh * g * e;
          zf[o] = z;
          zb[o] = f2bf(z);
          if (FINAL) out0[o] = z + Ub[o];
        } else {
          Cout[o] = f2bf(v);
        }
      }
    }
    if (STATS) {
      atomicAdd(&sS[nt * 16 + col], ls);
      atomicAdd(&sQ[nt * 16 + col], lq);
    }
  }

  if (STATS) {
    __syncthreads();
    if (tid < 64) {
      atomicAdd(&s1[n0 + tid], sS[tid]);
      atomicAdd(&s2[n0 + tid], sQ[tid]);
    }
  }
}

// X1 (cols 0..1023, stats) merged with T=tanh (cols 1024..1535). W = W1||Wd1.
__global__ __launch_bounds__(256, 3) void k_x1t(
    const ushort_t* __restrict__ zb, const ushort_t* __restrict__ Wcat,
    const void* __restrict__ bd1, ushort_t* __restrict__ Xb,
    ushort_t* __restrict__ Tb, float* __restrict__ s1, float* __restrict__ s2,
    const float* __restrict__ consts) {
  __shared__ __bf16 As[128 * 64] __attribute__((aligned(16)));
  __shared__ __bf16 Bs[64 * 64] __attribute__((aligned(16)));
  const int nb = blockIdx.x;  // 0..23
  const int m0 = blockIdx.y * 128, n0 = nb * 64;
  if (nb < 16) {
    gemm_body<2, 0, 1, 0, 0, 0>(zb, Wcat, nullptr, 0, Xb, 1024, 512, m0, n0,
                                As, Bs, s1, s2, nullptr, nullptr, nullptr,
                                nullptr, 0, consts, nullptr, nullptr);
  } else {
    gemm_body<2, 1, 0, 0, 1, 0>(zb, Wcat, bd1, -1024, Tb, 512, 512, m0, n0,
                                As, Bs, nullptr, nullptr, nullptr, nullptr,
                                nullptr, nullptr, 0, consts, nullptr, nullptr);
  }
}

// X2 (ids 0..511, stats) packed with G=softplus (ids 512..1023).
__global__ __launch_bounds__(256, 4) void k_x2g(
    const ushort_t* __restrict__ A1, const ushort_t* __restrict__ W2c,
    const ushort_t* __restrict__ Tb, const ushort_t* __restrict__ Wd2c,
    const void* __restrict__ bd2, ushort_t* __restrict__ Ab,
    ushort_t* __restrict__ Gb, float* __restrict__ s1, float* __restrict__ s2,
    const float* __restrict__ consts) {
  __shared__ __bf16 As[128 * 64] __attribute__((aligned(16)));
  __shared__ __bf16 Bs[64 * 64] __attribute__((aligned(16)));
  const int id = blockIdx.x;
  if (id < 512) {
    const int m0 = (id >> 4) * 128, n0 = (id & 15) * 64;
    gemm_body<2, 0, 1, 0, 0, 0>(A1, W2c, nullptr, 0, Ab, 1024, 1024, m0, n0,
                                As, Bs, s1, s2, nullptr, nullptr, nullptr,
                                nullptr, 0, consts, nullptr, nullptr);
  } else {
    const int gb = id - 512;
    const int m0 = (gb >> 3) * 64, n0 = (gb & 7) * 64;
    gemm_body<1, 2, 0, 0, 1, 0>(Tb, Wd2c, bd2, 0, Gb, 512, 512, m0, n0,
                                As, Bs, nullptr, nullptr, nullptr, nullptr,
                                nullptr, nullptr, 0, consts, nullptr, nullptr);
  }
}

// F = A2@W3^T + b3 with fused Euler update; FINAL also writes out0 = z + Ub.
template <int FINAL>
__global__ __launch_bounds__(256, 4) void k_fupd(
    const ushort_t* __restrict__ A2, const ushort_t* __restrict__ W3c,
    const void* __restrict__ b3, const ushort_t* __restrict__ Gb,
    float* __restrict__ zf, ushort_t* __restrict__ zb,
    const void* __restrict__ eps, unsigned long long eoff,
    const float* __restrict__ consts, const float* __restrict__ Ub,
    float* __restrict__ out0) {
  __shared__ __bf16 As[64 * 64] __attribute__((aligned(16)));
  __shared__ __bf16 Bs[64 * 64] __attribute__((aligned(16)));
  const int m0 = blockIdx.y * 64, n0 = blockIdx.x * 64;
  gemm_body<1, 0, 0, 1, 1, FINAL>(A2, W3c, b3, 0, nullptr, 512, 1024, m0, n0,
                                  As, Bs, nullptr, nullptr, Gb, zf, zb, eps,
                                  eoff, consts, Ub, out0);
}

// BN normalize + relu, in-place on bf16 X (8 elems/thread)
__global__ void bn_norm(ushort_t* __restrict__ X, const float* __restrict__ s1,
                        const float* __restrict__ s2, const void* __restrict__ g,
                        const void* __restrict__ be, const float* __restrict__ consts,
                        int N) {
  const int f32 = consts[3] != 0.f;
  const int i = blockIdx.x * 256 + threadIdx.x;
  const int c = (i * 8) % N;
  const float inv = 1.0f / 4096.0f;
  ushort4 x0 = ((const ushort4*)X)[i * 2];
  ushort4 x1 = ((const ushort4*)X)[i * 2 + 1];
  float xv[8] = {bf2f(x0.x), bf2f(x0.y), bf2f(x0.z), bf2f(x0.w),
                 bf2f(x1.x), bf2f(x1.y), bf2f(x1.z), bf2f(x1.w)};
  ushort_t o[8];
#pragma unroll
  for (int j = 0; j < 8; ++j) {
    float mu = s1[c + j] * inv;
    float var = fmaxf(s2[c + j] * inv - mu * mu, 0.f);
    float sc = ldin(g, c + j, f32) * rsqrtf(var + 1e-5f);
    float v = (xv[j] - mu) * sc + ldin(be, c + j, f32);
    o[j] = f2bf(fmaxf(v, 0.f));
  }
  ((ushort4*)X)[i * 2] = make_ushort4(o[0], o[1], o[2], o[3]);
  ((ushort4*)X)[i * 2 + 1] = make_ushort4(o[4], o[5], o[6], o[7]);
}

// zf (fp32 master) + zb (bf16 shadow) <- z_dyn
__global__ void k_init(const void* __restrict__ z, float* __restrict__ zf,
                       ushort_t* __restrict__ zb, const float* __restrict__ consts) {
  const int f32 = consts[3] != 0.f;
  const int i = blockIdx.x * 256 + threadIdx.x;
  float4 v;
  if (f32) {
    v = ((const float4*)z)[i];
  } else {
    ushort4 u = ((const ushort4*)z)[i];
    v = make_float4(bf2f(u.x), bf2f(u.y), bf2f(u.z), bf2f(u.w));
  }
  ((float4*)zf)[i] = v;
  ((ushort4*)zb)[i] = make_ushort4(f2bf(v.x), f2bf(v.y), f2bf(v.z), f2bf(v.w));
}

// Ub = dt*(ut@Bsde^T), fp32 (4096x512), LDS-tiled 64x64 K=64
__global__ __launch_bounds__(256) void k_ub(
    const void* __restrict__ ut, const void* __restrict__ Bsde,
    const float* __restrict__ consts, float* __restrict__ Ub) {
  __shared__ float As[64][68];
  __shared__ float Bs[64][68];
  const float dt = consts[2];
  const int f32 = consts[3] != 0.f;
  const int t = threadIdx.x;
  const int tx = t & 15, ty = t >> 4;
  const int n0 = blockIdx.x * 64, m0 = blockIdx.y * 64;
  const int r = t >> 2;
  const int c0 = (t & 3) * 16;

#pragma unroll
  for (int j = 0; j < 16; ++j) {
    As[c0 + j][r] = ldin(ut, (size_t)(m0 + r) * 64 + c0 + j, f32);
    Bs[c0 + j][r] = ldin(Bsde, (size_t)(n0 + r) * 64 + c0 + j, f32);
  }
  __syncthreads();

  float acc[4][4] = {};
#pragma unroll 8
  for (int kk = 0; kk < 64; ++kk) {
    float a[4], b[4];
    *(float4*)a = *(const float4*)&As[kk][ty * 4];
    *(float4*)b = *(const float4*)&Bs[kk][tx * 4];
#pragma unroll
    for (int i = 0; i < 4; ++i)
#pragma unroll
      for (int j = 0; j < 4; ++j) acc[i][j] += a[i] * b[j];
  }

#pragma unroll
  for (int i = 0; i < 4; ++i) {
    const size_t o = (size_t)(m0 + ty * 4 + i) * 512 + n0 + tx * 4;
    *(float4*)&Ub[o] = make_float4(dt * acc[i][0], dt * acc[i][1],
                                   dt * acc[i][2], dt * acc[i][3]);
  }
}

// Deff[j][k] = D[j][k] + sum_l C[j][l]*Bsde[l][k]  (25x64)
// 25 blocks x 256 threads: 4-way l-split + LDS reduce.
__global__ void k_deff(const void* __restrict__ Cm, const void* __restrict__ Bsde,
                       const void* __restrict__ Dm, const float* __restrict__ consts,
                       float* __restrict__ Deff) {
  __shared__ float red[4][64];
  const int f32 = consts[3] != 0.f;
  const int j = blockIdx.x;          // 0..24
  const int k = threadIdx.x & 63;    // 0..63
  const int part = threadIdx.x >> 6; // 0..3
  float acc = 0.f;
  const int l0 = part * 128;
#pragma unroll 8
  for (int l = l0; l < l0 + 128; ++l)
    acc += ldin(Cm, (size_t)j * 512 + l, f32) * ldin(Bsde, (size_t)l * 64 + k, f32);
  red[part][k] = acc;
  __syncthreads();
  if (part == 0) {
    float s = red[0][k] + red[1][k] + red[2][k] + red[3][k];
    Deff[j * 64 + k] = s + ldin(Dm, (size_t)j * 64 + k, f32);
  }
}

// yt = zf@C^T + dt*(ut@Deff^T): wave-per-row
__global__ __launch_bounds__(256) void k_final2(
    const float* __restrict__ zf, const void* __restrict__ ut,
    const float* __restrict__ consts, const void* __restrict__ Cm,
    const float* __restrict__ Deff, float* __restrict__ out1) {
  const float dt = consts[2];
  const int f32 = consts[3] != 0.f;
  const int t = threadIdx.x;
  const int lane = t & 63;
  const int m = blockIdx.x * 4 + (t >> 6);
  float z8[8];
#pragma unroll
  for (int i = 0; i < 8; ++i) z8[i] = zf[(size_t)m * 512 + i * 64 + lane];
  const float u = ldin(ut, (size_t)m * 64 + lane, f32);

  for (int j = 0; j < 25; ++j) {
    float p = dt * u * Deff[j * 64 + lane];
#pragma unroll
    for (int i = 0; i < 8; ++i)
      p += z8[i] * ldin(Cm, (size_t)j * 512 + i * 64 + lane, f32);
#pragma unroll
    for (int off = 32; off > 0; off >>= 1) p += __shfl_down(p, off, 64);
    if (lane == 0) out1[m * 25 + j] = p;
  }
}

// ---------------------------------------------------------------------------
extern "C" void kernel_launch(void* const* d_in, const int* in_sizes, int n_in,
                              void* d_out, int out_size, void* d_ws, size_t ws_size,
                              hipStream_t stream) {
  static const int expA[22] = {
      2097152, 524288, 1,      262144, 16777216, 524288, 1024, 1024,
      1024,    1048576, 1024,  1024,   1024,     524288, 512,  262144,
      512,     262144, 512,    32768,  12800,    1600};

  int map[21];
  bool okA = (n_in == 22), okB = (n_in == 21);
  if (okA)
    for (int i = 0; i < 22; ++i)
      if (in_sizes[i] != expA[i]) { okA = false; break; }
  if (okB) {
    int j = 0;
    for (int i = 0; i < 22; ++i) {
      if (i == 1) continue;
      if (in_sizes[j] != expA[i]) { okB = false; break; }
      ++j;
    }
  }
  if (okA) {
    map[0] = 0;
    for (int i = 1; i < 21; ++i) map[i] = i + 1;
  } else if (okB) {
    for (int i = 0; i < 21; ++i) map[i] = i;
  } else {
    map[0] = 0;
    for (int i = 1; i < 21; ++i) map[i] = (i + 1 < n_in) ? i + 1 : n_in - 1;
  }

  const void* z_dyn = d_in[map[0]];
  const void* dtp = d_in[map[1]];
  const void* ut = d_in[map[2]];
  const void* eps = d_in[map[3]];
  const void* W1 = d_in[map[4]];
  const void* g1 = d_in[map[6]];
  const void* be1 = d_in[map[7]];
  const void* W2 = d_in[map[8]];
  const void* g2 = d_in[map[10]];
  const void* be2 = d_in[map[11]];
  const void* W3 = d_in[map[12]];
  const void* b3 = d_in[map[13]];
  const void* Wd1 = d_in[map[14]];
  const void* bd1 = d_in[map[15]];
  const void* Wd2 = d_in[map[16]];
  const void* bd2 = d_in[map[17]];
  const void* Bsde = d_in[map[18]];
  const void* Cm = d_in[map[19]];
  const void* Dm = d_in[map[20]];

  // ws layout (~50 MB of 268 MB):
  //  [0,8M) zf fp32; [8,12M) zb bf16
  //  [12,20M) Xb bf16 (X1/A1); [20,28M) Ab bf16 (X2/A2)
  //  [28,32M) Tb bf16; [32,36M) Gb bf16; [36,44M) Ub fp32
  //  [44,49.25M) canon bf16 weights [W1|Wd1|W2|W3|Wd2]
  //  [49.5M) stats 16x2048 f32, consts, Deff
  char* ws = (char*)d_ws;
  const size_t MB = 1024 * 1024;
  float* zf = (float*)(ws + 0);
  ushort_t* zb = (ushort_t*)(ws + 8 * MB);
  ushort_t* Xb = (ushort_t*)(ws + 12 * MB);
  ushort_t* Ab = (ushort_t*)(ws + 20 * MB);
  ushort_t* Tb = (ushort_t*)(ws + 28 * MB);
  ushort_t* Gb = (ushort_t*)(ws + 32 * MB);
  float* Ub = (float*)(ws + 36 * MB);
  ushort_t* canon = (ushort_t*)(ws + 44 * MB);
  float* stats = (float*)(ws + 49 * MB + 512 * 1024);
  float* consts = stats + 16 * 2048;
  float* Deff = consts + 16;

  const ushort_t* Wcat = canon + 0;        // W1(1024)||Wd1(512) rows, K=512
  const ushort_t* W2c = canon + 786432;    // 1024 rows, K=1024
  const ushort_t* W3c = canon + 1835008;   // 512 rows, K=1024
  const ushort_t* Wd2c = canon + 2359296;  // 512 rows, K=512

  float* out_z = (float*)d_out;
  float* out_y = out_z + 4096 * 512;

  const dim3 blk(256);

  k_detect<<<1, blk, 0, stream>>>(eps, dtp, consts);

  ConvArgs ca;
  ca.src[0] = W1;
  ca.src[1] = Wd1;
  ca.src[2] = W2;
  ca.src[3] = W3;
  ca.src[4] = Wd2;
  k_conv<<<(CONV_TOT / 4 + 255) / 256, blk, 0, stream>>>(ca, consts, canon);

  hipMemsetAsync(stats, 0, 16 * 2048 * sizeof(float), stream);
  k_init<<<2048, blk, 0, stream>>>(z_dyn, zf, zb, consts);
  k_ub<<<dim3(8, 64), blk, 0, stream>>>(ut, Bsde, consts, Ub);
  k_deff<<<25, blk, 0, stream>>>(Cm, Bsde, Dm, consts, Deff);

  for (int s = 0; s < 8; ++s) {
    float* sA1 = stats + (s * 2 + 0) * 2048;
    float* sA2 = stats + (s * 2 + 1) * 2048;
    const unsigned long long eoff = (unsigned long long)s * 4096 * 512;

    // X1 (stats, no bias) || T = tanh(z@Wd1^T+bd1)
    k_x1t<<<dim3(24, 32), blk, 0, stream>>>(zb, Wcat, bd1, Xb, Tb,
                                            sA1, sA1 + 1024, consts);
    bn_norm<<<2048, blk, 0, stream>>>(Xb, sA1, sA1 + 1024, g1, be1, consts, 1024);

    // X2 (stats, no bias) packed with G = softplus(T@Wd2^T+bd2)+1e-5
    k_x2g<<<1024, blk, 0, stream>>>(Xb, W2c, Tb, Wd2c, bd2, Ab, Gb,
                                    sA2, sA2 + 1024, consts);
    bn_norm<<<2048, blk, 0, stream>>>(Ab, sA2, sA2 + 1024, g2, be2, consts, 1024);

    // F = A2@W3^T + b3, fused z += h*F + sh*G*eps; final step emits out0
    if (s < 7) {
      k_fupd<0><<<dim3(8, 64), blk, 0, stream>>>(Ab, W3c, b3, Gb, zf, zb, eps,
                                                 eoff, consts, Ub, out_z);
    } else {
      k_fupd<1><<<dim3(8, 64), blk, 0, stream>>>(Ab, W3c, b3, Gb, zf, zb, eps,
                                                 eoff, consts, Ub, out_z);
    }
  }

  k_final2<<<1024, blk, 0, stream>>>(zf, ut, consts, Cm, Deff, out_y);
}

// Round 13
// 1082.707 us; speedup vs baseline: 1.0501x; 1.0052x over previous
//
#include <hip/hip_runtime.h>

// ---------------------------------------------------------------------------
// ConditionedLatentSDETransition — MI355X (round 13: XCD-locality swizzle)
//
// Verified: inputs fp32 (runtime-detected), outputs fp32, ws ~268MB,
// dict-order inputs. Round-12: 1088 us, absmax 0.031.
//
// Theory: GEMMs are bound by A/W tile re-read traffic (~590 MB/step), not
// MFMA. Round-13: 1-D grids with XCD-aware decode — XCD q (blockIdx%8) owns
// m-strip q (A slice 0.5-1MB, fits 4MB per-XCD L2) and streams W through it
// (m fastest, n slowest within XCD). Off-XCD traffic ~590 -> ~130 MB/step.
// ---------------------------------------------------------------------------

typedef unsigned short ushort_t;
typedef __bf16 bf16x8 __attribute__((ext_vector_type(8)));
typedef float f32x4 __attribute__((ext_vector_type(4)));

__device__ __forceinline__ float bf2f(ushort_t s) {
  unsigned u = ((unsigned)s) << 16;
  return __uint_as_float(u);
}
__device__ __forceinline__ ushort_t f2bf(float f) {
  unsigned u = __float_as_uint(f);
  unsigned lsb = (u >> 16) & 1u;
  u += 0x7fffu + lsb;
  return (ushort_t)(u >> 16);
}
__device__ __forceinline__ float ldin(const void* p, size_t i, int f32) {
  return f32 ? ((const float*)p)[i] : bf2f(((const ushort_t*)p)[i]);
}
__device__ __forceinline__ void async16(const void* g, void* l) {
  __builtin_amdgcn_global_load_lds(
      (const __attribute__((address_space(1))) void*)g,
      (__attribute__((address_space(3))) void*)l, 16, 0, 0);
}

// consts: [0]=h, [1]=sqrt_h, [2]=dt, [3]=f32flag
__global__ void k_detect(const void* __restrict__ eps, const void* __restrict__ dtraw,
                         float* __restrict__ consts) {
  __shared__ float mx[256];
  const int t = threadIdx.x;
  const ushort_t* e = (const ushort_t*)eps;
  float m = 0.f;
#pragma unroll
  for (int k = 0; k < 4; ++k) {
    float v = fabsf(bf2f(e[t * 4 + k]));
    if (!(v < 1e30f)) v = 1e30f;
    m = fmaxf(m, v);
  }
  mx[t] = m;
  __syncthreads();
  if (t == 0) {
    float M = 0.f;
    for (int k = 0; k < 256; ++k) M = fmaxf(M, mx[k]);
    const int f32 = (M > 1e3f) ? 1 : 0;
    float dt;
    if (f32) {
      dt = *(const float*)dtraw;
    } else {
      float db = bf2f(*(const ushort_t*)dtraw);
      float df = *(const float*)dtraw;
      dt = (db > 1e-6f && db < 1e3f) ? db : df;
    }
    const float h = dt * 0.125f;
    consts[0] = h;
    consts[1] = sqrtf(fabsf(h) + 1e-8f);
    consts[2] = dt;
    consts[3] = (float)f32;
  }
}

// one-time: convert weights to bf16 canon: [W1 | Wd1 | W2 | W3 | Wd2]
struct ConvArgs { const void* src[5]; };
#define CONV_TOT 2621440

__global__ void k_conv(ConvArgs a, const float* __restrict__ consts,
                       ushort_t* __restrict__ base) {
  constexpr int CUM[6] = {0, 524288, 786432, 1835008, 2359296, 2621440};
  const int f32 = consts[3] != 0.f;
  const int i = (blockIdx.x * 256 + threadIdx.x) * 4;
  if (i >= CONV_TOT) return;
  int j = 0;
#pragma unroll
  for (int k = 1; k < 5; ++k)
    if (i >= CUM[k]) j = k;
  const int local = i - CUM[j];
  const void* s = a.src[j];
  ushort4 o;
  if (f32) {
    float4 v = ((const float4*)s)[local >> 2];
    o = make_ushort4(f2bf(v.x), f2bf(v.y), f2bf(v.z), f2bf(v.w));
  } else {
    o = ((const ushort4*)s)[local >> 2];
  }
  *(ushort4*)(base + i) = o;
}

// ---------------------------------------------------------------------------
// Generic MFMA GEMM body. BM = MT*64, BN=64, BK=64, 256 threads.
// MODE 0 plain, 1 tanh, 2 softplus+1e-5. BIAS: add bias[gn+ncol0].
// STATS: per-col sum/sumsq -> s1/s2 atomics. FUSE: Euler update epilogue.
// FINAL: (with FUSE) also out0 = z_new + Ub.
// ---------------------------------------------------------------------------
template <int MT, int MODE, int STATS, int FUSE, int BIAS, int FINAL>
__device__ __forceinline__ void gemm_body(
    const ushort_t* __restrict__ A, const ushort_t* __restrict__ W,
    const void* __restrict__ bias, int ncol0, ushort_t* __restrict__ Cout,
    int Nout, int K, int m0, int n0, __bf16* As, __bf16* Bs,
    float* __restrict__ s1, float* __restrict__ s2,
    const ushort_t* __restrict__ Gb, float* __restrict__ zf,
    ushort_t* __restrict__ zb, const void* __restrict__ eps,
    unsigned long long eoff, const float* __restrict__ consts,
    const float* __restrict__ Ub, float* __restrict__ out0) {
  constexpr int BM = MT * 64;
  const int f32 = consts[3] != 0.f;
  const int tid = threadIdx.x;
  const int lane = tid & 63;
  const int wave = tid >> 6;
  const int col = lane & 15;
  const int quad = lane >> 4;
  const int rowBase = wave * (BM / 4);

  f32x4 acc[MT][4] = {};

  for (int k0 = 0; k0 < K; k0 += 64) {
#pragma unroll
    for (int j = 0; j < BM / 32; ++j) {
      int chunk = j * 256 + tid;
      int row = chunk >> 3;
      int kc = chunk & 7;
      async16(A + (size_t)(m0 + row) * K + k0 + kc * 8, (char*)As + chunk * 16);
    }
#pragma unroll
    for (int j = 0; j < 2; ++j) {
      int chunk = j * 256 + tid;
      int row = chunk >> 3;
      int kc = chunk & 7;
      async16(W + (size_t)(n0 + row) * K + k0 + kc * 8, (char*)Bs + chunk * 16);
    }
    __syncthreads();

#pragma unroll
    for (int kk = 0; kk < 2; ++kk) {
      const int kb = kk * 32 + quad * 8;
      bf16x8 af[MT], bfr[4];
#pragma unroll
      for (int mt = 0; mt < MT; ++mt)
        af[mt] = *(const bf16x8*)&As[(rowBase + mt * 16 + col) * 64 + kb];
#pragma unroll
      for (int nt = 0; nt < 4; ++nt)
        bfr[nt] = *(const bf16x8*)&Bs[(nt * 16 + col) * 64 + kb];
#pragma unroll
      for (int mt = 0; mt < MT; ++mt)
#pragma unroll
        for (int nt = 0; nt < 4; ++nt)
          acc[mt][nt] = __builtin_amdgcn_mfma_f32_16x16x32_bf16(
              af[mt], bfr[nt], acc[mt][nt], 0, 0, 0);
    }
    __syncthreads();
  }

  float* sS = (float*)As;       // [64] stats scratch (reuses As)
  float* sQ = (float*)As + 64;
  if (STATS) {
    if (tid < 128) ((float*)As)[tid] = 0.f;
    __syncthreads();
  }

  const float h = consts[0], sh = consts[1];

#pragma unroll
  for (int nt = 0; nt < 4; ++nt) {
    const int gn = n0 + nt * 16 + col;
    const float bv = BIAS ? ldin(bias, gn + ncol0, f32) : 0.f;
    float ls = 0.f, lq = 0.f;
#pragma unroll
    for (int mt = 0; mt < MT; ++mt) {
#pragma unroll
      for (int r = 0; r < 4; ++r) {
        const int gm = m0 + rowBase + mt * 16 + quad * 4 + r;
        float v = acc[mt][nt][r] + bv;
        if (STATS) {
          ls += v;
          lq += v * v;
        }
        if (MODE == 1) {
          v = tanhf(v);
        } else if (MODE == 2) {
          v = fmaxf(v, 0.f) + log1pf(expf(-fabsf(v))) + 1e-5f;
        }
        const size_t o = (size_t)gm * Nout + gn + ncol0;
        if (FUSE) {
          const float e = ldin(eps, eoff + o, f32);
          const float g = bf2f(Gb[o]);
          const float z = zf[o] + h * v + sh * g * e;
          zf[o] = z;
          zb[o] = f2bf(z);
          if (FINAL) out0[o] = z + Ub[o];
        } else {
          Cout[o] = f2bf(v);
        }
      }
    }
    if (STATS) {
      atomicAdd(&sS[nt * 16 + col], ls);
      atomicAdd(&sQ[nt * 16 + col], lq);
    }
  }

  if (STATS) {
    __syncthreads();
    if (tid < 64) {
      atomicAdd(&s1[n0 + tid], sS[tid]);
      atomicAdd(&s2[n0 + tid], sQ[tid]);
    }
  }
}

// X1 (stats) merged with T=tanh. W = W1||Wd1 (1536 rows, K=512).
// 768 blocks: XCD q (L%8) owns m-strip q; m fastest, n slowest within XCD.
__global__ __launch_bounds__(256, 3) void k_x1t(
    const ushort_t* __restrict__ zb, const ushort_t* __restrict__ Wcat,
    const void* __restrict__ bd1, ushort_t* __restrict__ Xb,
    ushort_t* __restrict__ Tb, float* __restrict__ s1, float* __restrict__ s2,
    const float* __restrict__ consts) {
  __shared__ __bf16 As[128 * 64] __attribute__((aligned(16)));
  __shared__ __bf16 Bs[64 * 64] __attribute__((aligned(16)));
  const int L = blockIdx.x;            // 0..767
  const int q = L & 7, w = L >> 3;     // q: XCD, w: 0..95
  const int mloc = w & 3, n = w >> 2;  // 4 m-blocks x 24 n-strips
  const int m0 = (q * 4 + mloc) * 128;
  const int n0 = n * 64;
  if (n < 16) {
    gemm_body<2, 0, 1, 0, 0, 0>(zb, Wcat, nullptr, 0, Xb, 1024, 512, m0, n0,
                                As, Bs, s1, s2, nullptr, nullptr, nullptr,
                                nullptr, 0, consts, nullptr, nullptr);
  } else {
    gemm_body<2, 1, 0, 0, 1, 0>(zb, Wcat, bd1, -1024, Tb, 512, 512, m0, n0,
                                As, Bs, nullptr, nullptr, nullptr, nullptr,
                                nullptr, nullptr, 0, consts, nullptr, nullptr);
  }
}

// X2 (ids 0..511, stats) packed with G=softplus (ids 512..1023), XCD-swizzled.
__global__ __launch_bounds__(256, 4) void k_x2g(
    const ushort_t* __restrict__ A1, const ushort_t* __restrict__ W2c,
    const ushort_t* __restrict__ Tb, const ushort_t* __restrict__ Wd2c,
    const void* __restrict__ bd2, ushort_t* __restrict__ Ab,
    ushort_t* __restrict__ Gb, float* __restrict__ s1, float* __restrict__ s2,
    const float* __restrict__ consts) {
  __shared__ __bf16 As[128 * 64] __attribute__((aligned(16)));
  __shared__ __bf16 Bs[64 * 64] __attribute__((aligned(16)));
  const int L = blockIdx.x;
  if (L < 512) {
    const int q = L & 7, w = L >> 3;     // w: 0..63
    const int mloc = w & 3, n = w >> 2;  // 4 m-blocks x 16 n-strips
    const int m0 = (q * 4 + mloc) * 128, n0 = n * 64;
    gemm_body<2, 0, 1, 0, 0, 0>(A1, W2c, nullptr, 0, Ab, 1024, 1024, m0, n0,
                                As, Bs, s1, s2, nullptr, nullptr, nullptr,
                                nullptr, 0, consts, nullptr, nullptr);
  } else {
    const int Lg = L - 512;
    const int q = Lg & 7, w = Lg >> 3;   // w: 0..63
    const int mloc = w & 7, n = w >> 3;  // 8 m-blocks x 8 n-strips (BM=64)
    const int m0 = (q * 8 + mloc) * 64, n0 = n * 64;
    gemm_body<1, 2, 0, 0, 1, 0>(Tb, Wd2c, bd2, 0, Gb, 512, 512, m0, n0,
                                As, Bs, nullptr, nullptr, nullptr, nullptr,
                                nullptr, nullptr, 0, consts, nullptr, nullptr);
  }
}

// F = A2@W3^T + b3 fused Euler; FINAL also out0 = z + Ub. XCD-swizzled.
template <int FINAL>
__global__ __launch_bounds__(256, 4) void k_fupd(
    const ushort_t* __restrict__ A2, const ushort_t* __restrict__ W3c,
    const void* __restrict__ b3, const ushort_t* __restrict__ Gb,
    float* __restrict__ zf, ushort_t* __restrict__ zb,
    const void* __restrict__ eps, unsigned long long eoff,
    const float* __restrict__ consts, const float* __restrict__ Ub,
    float* __restrict__ out0) {
  __shared__ __bf16 As[64 * 64] __attribute__((aligned(16)));
  __shared__ __bf16 Bs[64 * 64] __attribute__((aligned(16)));
  const int L = blockIdx.x;            // 0..511
  const int q = L & 7, w = L >> 3;     // w: 0..63
  const int mloc = w & 7, n = w >> 3;  // 8 m-blocks x 8 n-strips
  const int m0 = (q * 8 + mloc) * 64, n0 = n * 64;
  gemm_body<1, 0, 0, 1, 1, FINAL>(A2, W3c, b3, 0, nullptr, 512, 1024, m0, n0,
                                  As, Bs, nullptr, nullptr, Gb, zf, zb, eps,
                                  eoff, consts, Ub, out0);
}

// BN normalize + relu, in-place on bf16 X (8 elems/thread)
__global__ void bn_norm(ushort_t* __restrict__ X, const float* __restrict__ s1,
                        const float* __restrict__ s2, const void* __restrict__ g,
                        const void* __restrict__ be, const float* __restrict__ consts,
                        int N) {
  const int f32 = consts[3] != 0.f;
  const int i = blockIdx.x * 256 + threadIdx.x;
  const int c = (i * 8) % N;
  const float inv = 1.0f / 4096.0f;
  ushort4 x0 = ((const ushort4*)X)[i * 2];
  ushort4 x1 = ((const ushort4*)X)[i * 2 + 1];
  float xv[8] = {bf2f(x0.x), bf2f(x0.y), bf2f(x0.z), bf2f(x0.w),
                 bf2f(x1.x), bf2f(x1.y), bf2f(x1.z), bf2f(x1.w)};
  ushort_t o[8];
#pragma unroll
  for (int j = 0; j < 8; ++j) {
    float mu = s1[c + j] * inv;
    float var = fmaxf(s2[c + j] * inv - mu * mu, 0.f);
    float sc = ldin(g, c + j, f32) * rsqrtf(var + 1e-5f);
    float v = (xv[j] - mu) * sc + ldin(be, c + j, f32);
    o[j] = f2bf(fmaxf(v, 0.f));
  }
  ((ushort4*)X)[i * 2] = make_ushort4(o[0], o[1], o[2], o[3]);
  ((ushort4*)X)[i * 2 + 1] = make_ushort4(o[4], o[5], o[6], o[7]);
}

// zf (fp32 master) + zb (bf16 shadow) <- z_dyn
__global__ void k_init(const void* __restrict__ z, float* __restrict__ zf,
                       ushort_t* __restrict__ zb, const float* __restrict__ consts) {
  const int f32 = consts[3] != 0.f;
  const int i = blockIdx.x * 256 + threadIdx.x;
  float4 v;
  if (f32) {
    v = ((const float4*)z)[i];
  } else {
    ushort4 u = ((const ushort4*)z)[i];
    v = make_float4(bf2f(u.x), bf2f(u.y), bf2f(u.z), bf2f(u.w));
  }
  ((float4*)zf)[i] = v;
  ((ushort4*)zb)[i] = make_ushort4(f2bf(v.x), f2bf(v.y), f2bf(v.z), f2bf(v.w));
}

// Ub = dt*(ut@Bsde^T), fp32 (4096x512), LDS-tiled 64x64 K=64
__global__ __launch_bounds__(256) void k_ub(
    const void* __restrict__ ut, const void* __restrict__ Bsde,
    const float* __restrict__ consts, float* __restrict__ Ub) {
  __shared__ float As[64][68];
  __shared__ float Bs[64][68];
  const float dt = consts[2];
  const int f32 = consts[3] != 0.f;
  const int t = threadIdx.x;
  const int tx = t & 15, ty = t >> 4;
  const int n0 = blockIdx.x * 64, m0 = blockIdx.y * 64;
  const int r = t >> 2;
  const int c0 = (t & 3) * 16;

#pragma unroll
  for (int j = 0; j < 16; ++j) {
    As[c0 + j][r] = ldin(ut, (size_t)(m0 + r) * 64 + c0 + j, f32);
    Bs[c0 + j][r] = ldin(Bsde, (size_t)(n0 + r) * 64 + c0 + j, f32);
  }
  __syncthreads();

  float acc[4][4] = {};
#pragma unroll 8
  for (int kk = 0; kk < 64; ++kk) {
    float a[4], b[4];
    *(float4*)a = *(const float4*)&As[kk][ty * 4];
    *(float4*)b = *(const float4*)&Bs[kk][tx * 4];
#pragma unroll
    for (int i = 0; i < 4; ++i)
#pragma unroll
      for (int j = 0; j < 4; ++j) acc[i][j] += a[i] * b[j];
  }

#pragma unroll
  for (int i = 0; i < 4; ++i) {
    const size_t o = (size_t)(m0 + ty * 4 + i) * 512 + n0 + tx * 4;
    *(float4*)&Ub[o] = make_float4(dt * acc[i][0], dt * acc[i][1],
                                   dt * acc[i][2], dt * acc[i][3]);
  }
}

// Deff[j][k] = D[j][k] + sum_l C[j][l]*Bsde[l][k]  (25x64)
__global__ void k_deff(const void* __restrict__ Cm, const void* __restrict__ Bsde,
                       const void* __restrict__ Dm, const float* __restrict__ consts,
                       float* __restrict__ Deff) {
  __shared__ float red[4][64];
  const int f32 = consts[3] != 0.f;
  const int j = blockIdx.x;          // 0..24
  const int k = threadIdx.x & 63;    // 0..63
  const int part = threadIdx.x >> 6; // 0..3
  float acc = 0.f;
  const int l0 = part * 128;
#pragma unroll 8
  for (int l = l0; l < l0 + 128; ++l)
    acc += ldin(Cm, (size_t)j * 512 + l, f32) * ldin(Bsde, (size_t)l * 64 + k, f32);
  red[part][k] = acc;
  __syncthreads();
  if (part == 0) {
    float s = red[0][k] + red[1][k] + red[2][k] + red[3][k];
    Deff[j * 64 + k] = s + ldin(Dm, (size_t)j * 64 + k, f32);
  }
}

// yt = zf@C^T + dt*(ut@Deff^T): wave-per-row
__global__ __launch_bounds__(256) void k_final2(
    const float* __restrict__ zf, const void* __restrict__ ut,
    const float* __restrict__ consts, const void* __restrict__ Cm,
    const float* __restrict__ Deff, float* __restrict__ out1) {
  const float dt = consts[2];
  const int f32 = consts[3] != 0.f;
  const int t = threadIdx.x;
  const int lane = t & 63;
  const int m = blockIdx.x * 4 + (t >> 6);
  float z8[8];
#pragma unroll
  for (int i = 0; i < 8; ++i) z8[i] = zf[(size_t)m * 512 + i * 64 + lane];
  const float u = ldin(ut, (size_t)m * 64 + lane, f32);

  for (int j = 0; j < 25; ++j) {
    float p = dt * u * Deff[j * 64 + lane];
#pragma unroll
    for (int i = 0; i < 8; ++i)
      p += z8[i] * ldin(Cm, (size_t)j * 512 + i * 64 + lane, f32);
#pragma unroll
    for (int off = 32; off > 0; off >>= 1) p += __shfl_down(p, off, 64);
    if (lane == 0) out1[m * 25 + j] = p;
  }
}

// ---------------------------------------------------------------------------
extern "C" void kernel_launch(void* const* d_in, const int* in_sizes, int n_in,
                              void* d_out, int out_size, void* d_ws, size_t ws_size,
                              hipStream_t stream) {
  static const int expA[22] = {
      2097152, 524288, 1,      262144, 16777216, 524288, 1024, 1024,
      1024,    1048576, 1024,  1024,   1024,     524288, 512,  262144,
      512,     262144, 512,    32768,  12800,    1600};

  int map[21];
  bool okA = (n_in == 22), okB = (n_in == 21);
  if (okA)
    for (int i = 0; i < 22; ++i)
      if (in_sizes[i] != expA[i]) { okA = false; break; }
  if (okB) {
    int j = 0;
    for (int i = 0; i < 22; ++i) {
      if (i == 1) continue;
      if (in_sizes[j] != expA[i]) { okB = false; break; }
      ++j;
    }
  }
  if (okA) {
    map[0] = 0;
    for (int i = 1; i < 21; ++i) map[i] = i + 1;
  } else if (okB) {
    for (int i = 0; i < 21; ++i) map[i] = i;
  } else {
    map[0] = 0;
    for (int i = 1; i < 21; ++i) map[i] = (i + 1 < n_in) ? i + 1 : n_in - 1;
  }

  const void* z_dyn = d_in[map[0]];
  const void* dtp = d_in[map[1]];
  const void* ut = d_in[map[2]];
  const void* eps = d_in[map[3]];
  const void* W1 = d_in[map[4]];
  const void* g1 = d_in[map[6]];
  const void* be1 = d_in[map[7]];
  const void* W2 = d_in[map[8]];
  const void* g2 = d_in[map[10]];
  const void* be2 = d_in[map[11]];
  const void* W3 = d_in[map[12]];
  const void* b3 = d_in[map[13]];
  const void* Wd1 = d_in[map[14]];
  const void* bd1 = d_in[map[15]];
  const void* Wd2 = d_in[map[16]];
  const void* bd2 = d_in[map[17]];
  const void* Bsde = d_in[map[18]];
  const void* Cm = d_in[map[19]];
  const void* Dm = d_in[map[20]];

  // ws layout (~50 MB of 268 MB):
  //  [0,8M) zf fp32; [8,12M) zb bf16
  //  [12,20M) Xb bf16 (X1/A1); [20,28M) Ab bf16 (X2/A2)
  //  [28,32M) Tb bf16; [32,36M) Gb bf16; [36,44M) Ub fp32
  //  [44,49.25M) canon bf16 weights [W1|Wd1|W2|W3|Wd2]
  //  [49.5M) stats 16x2048 f32, consts, Deff
  char* ws = (char*)d_ws;
  const size_t MB = 1024 * 1024;
  float* zf = (float*)(ws + 0);
  ushort_t* zb = (ushort_t*)(ws + 8 * MB);
  ushort_t* Xb = (ushort_t*)(ws + 12 * MB);
  ushort_t* Ab = (ushort_t*)(ws + 20 * MB);
  ushort_t* Tb = (ushort_t*)(ws + 28 * MB);
  ushort_t* Gb = (ushort_t*)(ws + 32 * MB);
  float* Ub = (float*)(ws + 36 * MB);
  ushort_t* canon = (ushort_t*)(ws + 44 * MB);
  float* stats = (float*)(ws + 49 * MB + 512 * 1024);
  float* consts = stats + 16 * 2048;
  float* Deff = consts + 16;

  const ushort_t* Wcat = canon + 0;        // W1(1024)||Wd1(512) rows, K=512
  const ushort_t* W2c = canon + 786432;    // 1024 rows, K=1024
  const ushort_t* W3c = canon + 1835008;   // 512 rows, K=1024
  const ushort_t* Wd2c = canon + 2359296;  // 512 rows, K=512

  float* out_z = (float*)d_out;
  float* out_y = out_z + 4096 * 512;

  const dim3 blk(256);

  k_detect<<<1, blk, 0, stream>>>(eps, dtp, consts);

  ConvArgs ca;
  ca.src[0] = W1;
  ca.src[1] = Wd1;
  ca.src[2] = W2;
  ca.src[3] = W3;
  ca.src[4] = Wd2;
  k_conv<<<(CONV_TOT / 4 + 255) / 256, blk, 0, stream>>>(ca, consts, canon);

  hipMemsetAsync(stats, 0, 16 * 2048 * sizeof(float), stream);
  k_init<<<2048, blk, 0, stream>>>(z_dyn, zf, zb, consts);
  k_ub<<<dim3(8, 64), blk, 0, stream>>>(ut, Bsde, consts, Ub);
  k_deff<<<25, blk, 0, stream>>>(Cm, Bsde, Dm, consts, Deff);

  for (int s = 0; s < 8; ++s) {
    float* sA1 = stats + (s * 2 + 0) * 2048;
    float* sA2 = stats + (s * 2 + 1) * 2048;
    const unsigned long long eoff = (unsigned long long)s * 4096 * 512;

    // X1 (stats, no bias) || T = tanh(z@Wd1^T+bd1), XCD-swizzled
    k_x1t<<<768, blk, 0, stream>>>(zb, Wcat, bd1, Xb, Tb,
                                   sA1, sA1 + 1024, consts);
    bn_norm<<<2048, blk, 0, stream>>>(Xb, sA1, sA1 + 1024, g1, be1, consts, 1024);

    // X2 (stats, no bias) packed with G = softplus(T@Wd2^T+bd2)+1e-5
    k_x2g<<<1024, blk, 0, stream>>>(Xb, W2c, Tb, Wd2c, bd2, Ab, Gb,
                                    sA2, sA2 + 1024, consts);
    bn_norm<<<2048, blk, 0, stream>>>(Ab, sA2, sA2 + 1024, g2, be2, consts, 1024);

    // F = A2@W3^T + b3, fused z += h*F + sh*G*eps; final step emits out0
    if (s < 7) {
      k_fupd<0><<<512, blk, 0, stream>>>(Ab, W3c, b3, Gb, zf, zb, eps,
                                         eoff, consts, Ub, out_z);
    } else {
      k_fupd<1><<<512, blk, 0, stream>>>(Ab, W3c, b3, Gb, zf, zb, eps,
                                         eoff, consts, Ub, out_z);
    }
  }

  k_final2<<<1024, blk, 0, stream>>>(zf, ut, consts, Cm, Deff, out_y);
}

// Round 14
// 879.470 us; speedup vs baseline: 1.2928x; 1.2311x over previous
//
#include <hip/hip_runtime.h>

// ---------------------------------------------------------------------------
// ConditionedLatentSDETransition — MI355X (round 14: BN folded into A-reads)
//
// Verified: inputs fp32 (runtime-detected), outputs fp32, ws ~268MB,
// dict-order inputs. Round-13: 1083 us, absmax 0.031. XCD swizzle neutral
// (traffic already L2/L3-absorbed) — bottleneck is dispatch count / chain
// depth (5 barriers/step).
//
// Round-14: bn_norm eliminated. X1/X2 stored RAW (bias-free, stats in
// epilogue); consumer GEMMs apply relu(x*sc+sh) while decoding A-fragments
// (sc/sh per K-column precomputed into LDS from grid-finalized stats).
// 3 dispatches/step: x1t -> x2g -> fupd.
// ---------------------------------------------------------------------------

typedef unsigned short ushort_t;
typedef __bf16 bf16x8 __attribute__((ext_vector_type(8)));
typedef float f32x4 __attribute__((ext_vector_type(4)));

__device__ __forceinline__ float bf2f(ushort_t s) {
  unsigned u = ((unsigned)s) << 16;
  return __uint_as_float(u);
}
__device__ __forceinline__ ushort_t f2bf(float f) {
  unsigned u = __float_as_uint(f);
  unsigned lsb = (u >> 16) & 1u;
  u += 0x7fffu + lsb;
  return (ushort_t)(u >> 16);
}
__device__ __forceinline__ float ldin(const void* p, size_t i, int f32) {
  return f32 ? ((const float*)p)[i] : bf2f(((const ushort_t*)p)[i]);
}
__device__ __forceinline__ void async16(const void* g, void* l) {
  __builtin_amdgcn_global_load_lds(
      (const __attribute__((address_space(1))) void*)g,
      (__attribute__((address_space(3))) void*)l, 16, 0, 0);
}

// consts: [0]=h, [1]=sqrt_h, [2]=dt, [3]=f32flag
__global__ void k_detect(const void* __restrict__ eps, const void* __restrict__ dtraw,
                         float* __restrict__ consts) {
  __shared__ float mx[256];
  const int t = threadIdx.x;
  const ushort_t* e = (const ushort_t*)eps;
  float m = 0.f;
#pragma unroll
  for (int k = 0; k < 4; ++k) {
    float v = fabsf(bf2f(e[t * 4 + k]));
    if (!(v < 1e30f)) v = 1e30f;
    m = fmaxf(m, v);
  }
  mx[t] = m;
  __syncthreads();
  if (t == 0) {
    float M = 0.f;
    for (int k = 0; k < 256; ++k) M = fmaxf(M, mx[k]);
    const int f32 = (M > 1e3f) ? 1 : 0;
    float dt;
    if (f32) {
      dt = *(const float*)dtraw;
    } else {
      float db = bf2f(*(const ushort_t*)dtraw);
      float df = *(const float*)dtraw;
      dt = (db > 1e-6f && db < 1e3f) ? db : df;
    }
    const float h = dt * 0.125f;
    consts[0] = h;
    consts[1] = sqrtf(fabsf(h) + 1e-8f);
    consts[2] = dt;
    consts[3] = (float)f32;
  }
}

// one-time: convert weights to bf16 canon: [W1 | Wd1 | W2 | W3 | Wd2]
struct ConvArgs { const void* src[5]; };
#define CONV_TOT 2621440

__global__ void k_conv(ConvArgs a, const float* __restrict__ consts,
                       ushort_t* __restrict__ base) {
  constexpr int CUM[6] = {0, 524288, 786432, 1835008, 2359296, 2621440};
  const int f32 = consts[3] != 0.f;
  const int i = (blockIdx.x * 256 + threadIdx.x) * 4;
  if (i >= CONV_TOT) return;
  int j = 0;
#pragma unroll
  for (int k = 1; k < 5; ++k)
    if (i >= CUM[k]) j = k;
  const int local = i - CUM[j];
  const void* s = a.src[j];
  ushort4 o;
  if (f32) {
    float4 v = ((const float4*)s)[local >> 2];
    o = make_ushort4(f2bf(v.x), f2bf(v.y), f2bf(v.z), f2bf(v.w));
  } else {
    o = ((const ushort4*)s)[local >> 2];
  }
  *(ushort4*)(base + i) = o;
}

// ---------------------------------------------------------------------------
// Generic MFMA GEMM body. BM = MT*64, BN=64, BK=64, 256 threads.
// MODE 0 plain, 1 tanh, 2 softplus+1e-5. BIAS: add bias[gn+ncol0].
// STATS: per-col sum/sumsq -> s1/s2 atomics. FUSE: Euler update epilogue.
// FINAL: (with FUSE) also out0 = z_new + Ub.
// ANORM: A-fragments pass through relu(x*sc+sh) (BN folded into read);
//        sc/sh computed in prologue from s1in/s2in/gsc/gbe into LDS scF/shF.
// ---------------------------------------------------------------------------
template <int MT, int MODE, int STATS, int FUSE, int BIAS, int FINAL, int ANORM>
__device__ __forceinline__ void gemm_body(
    const ushort_t* __restrict__ A, const ushort_t* __restrict__ W,
    const void* __restrict__ bias, int ncol0, ushort_t* __restrict__ Cout,
    int Nout, int K, int m0, int n0, __bf16* As, __bf16* Bs,
    float* __restrict__ s1, float* __restrict__ s2,
    const ushort_t* __restrict__ Gb, float* __restrict__ zf,
    ushort_t* __restrict__ zb, const void* __restrict__ eps,
    unsigned long long eoff, const float* __restrict__ consts,
    const float* __restrict__ Ub, float* __restrict__ out0,
    const float* __restrict__ s1in, const float* __restrict__ s2in,
    const void* __restrict__ gsc, const void* __restrict__ gbe,
    float* scF, float* shF) {
  constexpr int BM = MT * 64;
  const int f32 = consts[3] != 0.f;
  const int tid = threadIdx.x;
  const int lane = tid & 63;
  const int wave = tid >> 6;
  const int col = lane & 15;
  const int quad = lane >> 4;
  const int rowBase = wave * (BM / 4);

  if (ANORM) {
    const float inv = 1.0f / 4096.0f;
    for (int c = tid; c < K; c += 256) {
      float mu = s1in[c] * inv;
      float var = fmaxf(s2in[c] * inv - mu * mu, 0.f);
      float sc = ldin(gsc, c, f32) * rsqrtf(var + 1e-5f);
      scF[c] = sc;
      shF[c] = ldin(gbe, c, f32) - mu * sc;
    }
  }

  f32x4 acc[MT][4] = {};

  for (int k0 = 0; k0 < K; k0 += 64) {
#pragma unroll
    for (int j = 0; j < BM / 32; ++j) {
      int chunk = j * 256 + tid;
      int row = chunk >> 3;
      int kc = chunk & 7;
      async16(A + (size_t)(m0 + row) * K + k0 + kc * 8, (char*)As + chunk * 16);
    }
#pragma unroll
    for (int j = 0; j < 2; ++j) {
      int chunk = j * 256 + tid;
      int row = chunk >> 3;
      int kc = chunk & 7;
      async16(W + (size_t)(n0 + row) * K + k0 + kc * 8, (char*)Bs + chunk * 16);
    }
    __syncthreads();  // also covers scF/shF prologue writes (first iter)

#pragma unroll
    for (int kk = 0; kk < 2; ++kk) {
      const int kb = kk * 32 + quad * 8;
      bf16x8 af[MT], bfr[4];
      if (ANORM) {
        float sc8[8], sh8[8];
        *(float4*)&sc8[0] = *(const float4*)&scF[k0 + kb];
        *(float4*)&sc8[4] = *(const float4*)&scF[k0 + kb + 4];
        *(float4*)&sh8[0] = *(const float4*)&shF[k0 + kb];
        *(float4*)&sh8[4] = *(const float4*)&shF[k0 + kb + 4];
#pragma unroll
        for (int mt = 0; mt < MT; ++mt) {
          bf16x8 raw = *(const bf16x8*)&As[(rowBase + mt * 16 + col) * 64 + kb];
#pragma unroll
          for (int j = 0; j < 8; ++j)
            af[mt][j] =
                (__bf16)fmaxf(fmaf((float)raw[j], sc8[j], sh8[j]), 0.f);
        }
      } else {
#pragma unroll
        for (int mt = 0; mt < MT; ++mt)
          af[mt] = *(const bf16x8*)&As[(rowBase + mt * 16 + col) * 64 + kb];
      }
#pragma unroll
      for (int nt = 0; nt < 4; ++nt)
        bfr[nt] = *(const bf16x8*)&Bs[(nt * 16 + col) * 64 + kb];
#pragma unroll
      for (int mt = 0; mt < MT; ++mt)
#pragma unroll
        for (int nt = 0; nt < 4; ++nt)
          acc[mt][nt] = __builtin_amdgcn_mfma_f32_16x16x32_bf16(
              af[mt], bfr[nt], acc[mt][nt], 0, 0, 0);
    }
    __syncthreads();
  }

  float* sS = (float*)As;       // [64] stats scratch (reuses As)
  float* sQ = (float*)As + 64;
  if (STATS) {
    if (tid < 128) ((float*)As)[tid] = 0.f;
    __syncthreads();
  }

  const float h = consts[0], sh = consts[1];

#pragma unroll
  for (int nt = 0; nt < 4; ++nt) {
    const int gn = n0 + nt * 16 + col;
    const float bv = BIAS ? ldin(bias, gn + ncol0, f32) : 0.f;
    float ls = 0.f, lq = 0.f;
#pragma unroll
    for (int mt = 0; mt < MT; ++mt) {
#pragma unroll
      for (int r = 0; r < 4; ++r) {
        const int gm = m0 + rowBase + mt * 16 + quad * 4 + r;
        float v = acc[mt][nt][r] + bv;
        if (STATS) {
          ls += v;
          lq += v * v;
        }
        if (MODE == 1) {
          v = tanhf(v);
        } else if (MODE == 2) {
          v = fmaxf(v, 0.f) + log1pf(expf(-fabsf(v))) + 1e-5f;
        }
        const size_t o = (size_t)gm * Nout + gn + ncol0;
        if (FUSE) {
          const float e = ldin(eps, eoff + o, f32);
          const float g = bf2f(Gb[o]);
          const float z = zf[o] + h * v + sh * g * e;
          zf[o] = z;
          zb[o] = f2bf(z);
          if (FINAL) out0[o] = z + Ub[o];
        } else {
          Cout[o] = f2bf(v);
        }
      }
    }
    if (STATS) {
      atomicAdd(&sS[nt * 16 + col], ls);
      atomicAdd(&sQ[nt * 16 + col], lq);
    }
  }

  if (STATS) {
    __syncthreads();
    if (tid < 64) {
      atomicAdd(&s1[n0 + tid], sS[tid]);
      atomicAdd(&s2[n0 + tid], sQ[tid]);
    }
  }
}

// X1 raw (stats) merged with T=tanh. W = W1||Wd1 (1536 rows, K=512).
__global__ __launch_bounds__(256, 3) void k_x1t(
    const ushort_t* __restrict__ zb, const ushort_t* __restrict__ Wcat,
    const void* __restrict__ bd1, ushort_t* __restrict__ Xb,
    ushort_t* __restrict__ Tb, float* __restrict__ s1, float* __restrict__ s2,
    const float* __restrict__ consts) {
  __shared__ __bf16 As[128 * 64] __attribute__((aligned(16)));
  __shared__ __bf16 Bs[64 * 64] __attribute__((aligned(16)));
  const int L = blockIdx.x;            // 0..767
  const int q = L & 7, w = L >> 3;
  const int mloc = w & 3, n = w >> 2;  // 4 m-blocks x 24 n-strips
  const int m0 = (q * 4 + mloc) * 128;
  const int n0 = n * 64;
  if (n < 16) {
    gemm_body<2, 0, 1, 0, 0, 0, 0>(zb, Wcat, nullptr, 0, Xb, 1024, 512, m0, n0,
                                   As, Bs, s1, s2, nullptr, nullptr, nullptr,
                                   nullptr, 0, consts, nullptr, nullptr,
                                   nullptr, nullptr, nullptr, nullptr,
                                   nullptr, nullptr);
  } else {
    gemm_body<2, 1, 0, 0, 1, 0, 0>(zb, Wcat, bd1, -1024, Tb, 512, 512, m0, n0,
                                   As, Bs, nullptr, nullptr, nullptr, nullptr,
                                   nullptr, nullptr, 0, consts, nullptr,
                                   nullptr, nullptr, nullptr, nullptr, nullptr,
                                   nullptr, nullptr);
  }
}

// X2 raw (stats2, A=bn(X1raw) on the fly) packed with G=softplus(T@Wd2+bd2).
__global__ __launch_bounds__(256, 3) void k_x2g(
    const ushort_t* __restrict__ X1raw, const ushort_t* __restrict__ W2c,
    const ushort_t* __restrict__ Tb, const ushort_t* __restrict__ Wd2c,
    const void* __restrict__ bd2, ushort_t* __restrict__ Ab,
    ushort_t* __restrict__ Gb, float* __restrict__ s1o, float* __restrict__ s2o,
    const float* __restrict__ s1i, const float* __restrict__ s2i,
    const void* __restrict__ g1, const void* __restrict__ be1,
    const float* __restrict__ consts) {
  __shared__ __bf16 As[128 * 64] __attribute__((aligned(16)));
  __shared__ __bf16 Bs[64 * 64] __attribute__((aligned(16)));
  __shared__ float scF[1024], shF[1024];
  const int L = blockIdx.x;
  if (L < 512) {
    const int q = L & 7, w = L >> 3;
    const int mloc = w & 3, n = w >> 2;  // 4 m-blocks x 16 n-strips
    const int m0 = (q * 4 + mloc) * 128, n0 = n * 64;
    gemm_body<2, 0, 1, 0, 0, 0, 1>(X1raw, W2c, nullptr, 0, Ab, 1024, 1024, m0,
                                   n0, As, Bs, s1o, s2o, nullptr, nullptr,
                                   nullptr, nullptr, 0, consts, nullptr,
                                   nullptr, s1i, s2i, g1, be1, scF, shF);
  } else {
    const int Lg = L - 512;
    const int q = Lg & 7, w = Lg >> 3;
    const int mloc = w & 7, n = w >> 3;  // 8 m-blocks x 8 n-strips (BM=64)
    const int m0 = (q * 8 + mloc) * 64, n0 = n * 64;
    gemm_body<1, 2, 0, 0, 1, 0, 0>(Tb, Wd2c, bd2, 0, Gb, 512, 512, m0, n0,
                                   As, Bs, nullptr, nullptr, nullptr, nullptr,
                                   nullptr, nullptr, 0, consts, nullptr,
                                   nullptr, nullptr, nullptr, nullptr, nullptr,
                                   nullptr, nullptr);
  }
}

// F = bn(X2raw)@W3^T + b3 (A-norm on the fly) with fused Euler update.
template <int FINAL>
__global__ __launch_bounds__(256, 4) void k_fupd(
    const ushort_t* __restrict__ X2raw, const ushort_t* __restrict__ W3c,
    const void* __restrict__ b3, const ushort_t* __restrict__ Gb,
    float* __restrict__ zf, ushort_t* __restrict__ zb,
    const void* __restrict__ eps, unsigned long long eoff,
    const float* __restrict__ consts, const float* __restrict__ Ub,
    float* __restrict__ out0, const float* __restrict__ s1i,
    const float* __restrict__ s2i, const void* __restrict__ g2,
    const void* __restrict__ be2) {
  __shared__ __bf16 As[64 * 64] __attribute__((aligned(16)));
  __shared__ __bf16 Bs[64 * 64] __attribute__((aligned(16)));
  __shared__ float scF[1024], shF[1024];
  const int L = blockIdx.x;            // 0..511
  const int q = L & 7, w = L >> 3;
  const int mloc = w & 7, n = w >> 3;  // 8 m-blocks x 8 n-strips
  const int m0 = (q * 8 + mloc) * 64, n0 = n * 64;
  gemm_body<1, 0, 0, 1, 1, FINAL, 1>(X2raw, W3c, b3, 0, nullptr, 512, 1024,
                                     m0, n0, As, Bs, nullptr, nullptr, Gb, zf,
                                     zb, eps, eoff, consts, Ub, out0, s1i,
                                     s2i, g2, be2, scF, shF);
}

// zf (fp32 master) + zb (bf16 shadow) <- z_dyn
__global__ void k_init(const void* __restrict__ z, float* __restrict__ zf,
                       ushort_t* __restrict__ zb, const float* __restrict__ consts) {
  const int f32 = consts[3] != 0.f;
  const int i = blockIdx.x * 256 + threadIdx.x;
  float4 v;
  if (f32) {
    v = ((const float4*)z)[i];
  } else {
    ushort4 u = ((const ushort4*)z)[i];
    v = make_float4(bf2f(u.x), bf2f(u.y), bf2f(u.z), bf2f(u.w));
  }
  ((float4*)zf)[i] = v;
  ((ushort4*)zb)[i] = make_ushort4(f2bf(v.x), f2bf(v.y), f2bf(v.z), f2bf(v.w));
}

// Ub = dt*(ut@Bsde^T), fp32 (4096x512), LDS-tiled 64x64 K=64
__global__ __launch_bounds__(256) void k_ub(
    const void* __restrict__ ut, const void* __restrict__ Bsde,
    const float* __restrict__ consts, float* __restrict__ Ub) {
  __shared__ float As[64][68];
  __shared__ float Bs[64][68];
  const float dt = consts[2];
  const int f32 = consts[3] != 0.f;
  const int t = threadIdx.x;
  const int tx = t & 15, ty = t >> 4;
  const int n0 = blockIdx.x * 64, m0 = blockIdx.y * 64;
  const int r = t >> 2;
  const int c0 = (t & 3) * 16;

#pragma unroll
  for (int j = 0; j < 16; ++j) {
    As[c0 + j][r] = ldin(ut, (size_t)(m0 + r) * 64 + c0 + j, f32);
    Bs[c0 + j][r] = ldin(Bsde, (size_t)(n0 + r) * 64 + c0 + j, f32);
  }
  __syncthreads();

  float acc[4][4] = {};
#pragma unroll 8
  for (int kk = 0; kk < 64; ++kk) {
    float a[4], b[4];
    *(float4*)a = *(const float4*)&As[kk][ty * 4];
    *(float4*)b = *(const float4*)&Bs[kk][tx * 4];
#pragma unroll
    for (int i = 0; i < 4; ++i)
#pragma unroll
      for (int j = 0; j < 4; ++j) acc[i][j] += a[i] * b[j];
  }

#pragma unroll
  for (int i = 0; i < 4; ++i) {
    const size_t o = (size_t)(m0 + ty * 4 + i) * 512 + n0 + tx * 4;
    *(float4*)&Ub[o] = make_float4(dt * acc[i][0], dt * acc[i][1],
                                   dt * acc[i][2], dt * acc[i][3]);
  }
}

// Deff[j][k] = D[j][k] + sum_l C[j][l]*Bsde[l][k]  (25x64)
__global__ void k_deff(const void* __restrict__ Cm, const void* __restrict__ Bsde,
                       const void* __restrict__ Dm, const float* __restrict__ consts,
                       float* __restrict__ Deff) {
  __shared__ float red[4][64];
  const int f32 = consts[3] != 0.f;
  const int j = blockIdx.x;
  const int k = threadIdx.x & 63;
  const int part = threadIdx.x >> 6;
  float acc = 0.f;
  const int l0 = part * 128;
#pragma unroll 8
  for (int l = l0; l < l0 + 128; ++l)
    acc += ldin(Cm, (size_t)j * 512 + l, f32) * ldin(Bsde, (size_t)l * 64 + k, f32);
  red[part][k] = acc;
  __syncthreads();
  if (part == 0) {
    float s = red[0][k] + red[1][k] + red[2][k] + red[3][k];
    Deff[j * 64 + k] = s + ldin(Dm, (size_t)j * 64 + k, f32);
  }
}

// yt = zf@C^T + dt*(ut@Deff^T): wave-per-row
__global__ __launch_bounds__(256) void k_final2(
    const float* __restrict__ zf, const void* __restrict__ ut,
    const float* __restrict__ consts, const void* __restrict__ Cm,
    const float* __restrict__ Deff, float* __restrict__ out1) {
  const float dt = consts[2];
  const int f32 = consts[3] != 0.f;
  const int t = threadIdx.x;
  const int lane = t & 63;
  const int m = blockIdx.x * 4 + (t >> 6);
  float z8[8];
#pragma unroll
  for (int i = 0; i < 8; ++i) z8[i] = zf[(size_t)m * 512 + i * 64 + lane];
  const float u = ldin(ut, (size_t)m * 64 + lane, f32);

  for (int j = 0; j < 25; ++j) {
    float p = dt * u * Deff[j * 64 + lane];
#pragma unroll
    for (int i = 0; i < 8; ++i)
      p += z8[i] * ldin(Cm, (size_t)j * 512 + i * 64 + lane, f32);
#pragma unroll
    for (int off = 32; off > 0; off >>= 1) p += __shfl_down(p, off, 64);
    if (lane == 0) out1[m * 25 + j] = p;
  }
}

// ---------------------------------------------------------------------------
extern "C" void kernel_launch(void* const* d_in, const int* in_sizes, int n_in,
                              void* d_out, int out_size, void* d_ws, size_t ws_size,
                              hipStream_t stream) {
  static const int expA[22] = {
      2097152, 524288, 1,      262144, 16777216, 524288, 1024, 1024,
      1024,    1048576, 1024,  1024,   1024,     524288, 512,  262144,
      512,     262144, 512,    32768,  12800,    1600};

  int map[21];
  bool okA = (n_in == 22), okB = (n_in == 21);
  if (okA)
    for (int i = 0; i < 22; ++i)
      if (in_sizes[i] != expA[i]) { okA = false; break; }
  if (okB) {
    int j = 0;
    for (int i = 0; i < 22; ++i) {
      if (i == 1) continue;
      if (in_sizes[j] != expA[i]) { okB = false; break; }
      ++j;
    }
  }
  if (okA) {
    map[0] = 0;
    for (int i = 1; i < 21; ++i) map[i] = i + 1;
  } else if (okB) {
    for (int i = 0; i < 21; ++i) map[i] = i;
  } else {
    map[0] = 0;
    for (int i = 1; i < 21; ++i) map[i] = (i + 1 < n_in) ? i + 1 : n_in - 1;
  }

  const void* z_dyn = d_in[map[0]];
  const void* dtp = d_in[map[1]];
  const void* ut = d_in[map[2]];
  const void* eps = d_in[map[3]];
  const void* W1 = d_in[map[4]];
  const void* g1 = d_in[map[6]];
  const void* be1 = d_in[map[7]];
  const void* W2 = d_in[map[8]];
  const void* g2 = d_in[map[10]];
  const void* be2 = d_in[map[11]];
  const void* W3 = d_in[map[12]];
  const void* b3 = d_in[map[13]];
  const void* Wd1 = d_in[map[14]];
  const void* bd1 = d_in[map[15]];
  const void* Wd2 = d_in[map[16]];
  const void* bd2 = d_in[map[17]];
  const void* Bsde = d_in[map[18]];
  const void* Cm = d_in[map[19]];
  const void* Dm = d_in[map[20]];

  // ws layout (~50 MB of 268 MB):
  //  [0,8M) zf fp32; [8,12M) zb bf16
  //  [12,20M) Xb bf16 raw X1; [20,28M) Ab bf16 raw X2
  //  [28,32M) Tb bf16; [32,36M) Gb bf16; [36,44M) Ub fp32
  //  [44,49.25M) canon bf16 weights [W1|Wd1|W2|W3|Wd2]
  //  [49.5M) stats 16x2048 f32, consts, Deff
  char* ws = (char*)d_ws;
  const size_t MB = 1024 * 1024;
  float* zf = (float*)(ws + 0);
  ushort_t* zb = (ushort_t*)(ws + 8 * MB);
  ushort_t* Xb = (ushort_t*)(ws + 12 * MB);
  ushort_t* Ab = (ushort_t*)(ws + 20 * MB);
  ushort_t* Tb = (ushort_t*)(ws + 28 * MB);
  ushort_t* Gb = (ushort_t*)(ws + 32 * MB);
  float* Ub = (float*)(ws + 36 * MB);
  ushort_t* canon = (ushort_t*)(ws + 44 * MB);
  float* stats = (float*)(ws + 49 * MB + 512 * 1024);
  float* consts = stats + 16 * 2048;
  float* Deff = consts + 16;

  const ushort_t* Wcat = canon + 0;
  const ushort_t* W2c = canon + 786432;
  const ushort_t* W3c = canon + 1835008;
  const ushort_t* Wd2c = canon + 2359296;

  float* out_z = (float*)d_out;
  float* out_y = out_z + 4096 * 512;

  const dim3 blk(256);

  k_detect<<<1, blk, 0, stream>>>(eps, dtp, consts);

  ConvArgs ca;
  ca.src[0] = W1;
  ca.src[1] = Wd1;
  ca.src[2] = W2;
  ca.src[3] = W3;
  ca.src[4] = Wd2;
  k_conv<<<(CONV_TOT / 4 + 255) / 256, blk, 0, stream>>>(ca, consts, canon);

  hipMemsetAsync(stats, 0, 16 * 2048 * sizeof(float), stream);
  k_init<<<2048, blk, 0, stream>>>(z_dyn, zf, zb, consts);
  k_ub<<<dim3(8, 64), blk, 0, stream>>>(ut, Bsde, consts, Ub);
  k_deff<<<25, blk, 0, stream>>>(Cm, Bsde, Dm, consts, Deff);

  for (int s = 0; s < 8; ++s) {
    float* sA1 = stats + (s * 2 + 0) * 2048;
    float* sA2 = stats + (s * 2 + 1) * 2048;
    const unsigned long long eoff = (unsigned long long)s * 4096 * 512;

    // X1 raw (stats1) || T = tanh(z@Wd1^T+bd1)
    k_x1t<<<768, blk, 0, stream>>>(zb, Wcat, bd1, Xb, Tb,
                                   sA1, sA1 + 1024, consts);

    // X2 raw (stats2; A = relu(bn(X1raw)) on-the-fly) || G = softplus(...)
    k_x2g<<<1024, blk, 0, stream>>>(Xb, W2c, Tb, Wd2c, bd2, Ab, Gb,
                                    sA2, sA2 + 1024, sA1, sA1 + 1024,
                                    g1, be1, consts);

    // F = relu(bn(X2raw))@W3^T + b3, fused z += h*F + sh*G*eps
    if (s < 7) {
      k_fupd<0><<<512, blk, 0, stream>>>(Ab, W3c, b3, Gb, zf, zb, eps, eoff,
                                         consts, Ub, out_z, sA2, sA2 + 1024,
                                         g2, be2);
    } else {
      k_fupd<1><<<512, blk, 0, stream>>>(Ab, W3c, b3, Gb, zf, zb, eps, eoff,
                                         consts, Ub, out_z, sA2, sA2 + 1024,
                                         g2, be2);
    }
  }

  k_final2<<<1024, blk, 0, stream>>>(zf, ut, consts, Cm, Deff, out_y);
}